// Round 4
// baseline (15321.519 us; speedup 1.0000x reference)
//
#include <hip/hip_runtime.h>
#include <hip/hip_bf16.h>

#define INF_F 1000000000000.0f

typedef __attribute__((ext_vector_type(8))) short bfrag8;
typedef __attribute__((ext_vector_type(4))) float facc4;

__device__ __forceinline__ float sigf(float x){ return 1.0f/(1.0f + expf(-x)); }

// out-region offsets (floats)
#define OFF_LOG 0ull
#define OFF_A   32819200ull
#define OFF_C   33228800ull
#define OFF_E   33638400ull

// ---------------- init (also zeroes grid-barrier state each launch) ----------------
__global__ __launch_bounds__(256) void k_init(const float* __restrict__ init_s,
    float* __restrict__ hbuf, float* __restrict__ c0, float* __restrict__ ctxb,
    float* __restrict__ cov, unsigned* __restrict__ bar) {
  int i = blockIdx.x*256 + threadIdx.x;
  if (i < 32*512) { float v = init_s[i]; hbuf[i]=v; c0[i]=v; ctxb[i]=0.0f; }
  if (i < 32*400) cov[i] = 0.0f;
  if (i < 2048) bar[i] = 0u;
}

// ---------------- b_combo = W_ih@b_red + b_ih + b_hh ----------------
__global__ __launch_bounds__(256) void k_bcombo(const float* __restrict__ W_ih,
    const float* __restrict__ b_red, const float* __restrict__ b_ih,
    const float* __restrict__ b_hh, float* __restrict__ bcomb) {
  int j = blockIdx.x*256 + threadIdx.x;
  if (j >= 2048) return;
  float acc = b_ih[j] + b_hh[j];
  for (int m=0;m<300;m++) acc += W_ih[j*300+m]*b_red[m];
  bcomb[j] = acc;
}

// ---------------- Wct[2048][812] = W_ih[2048x300] @ W_red[300x812] ----------------
__global__ __launch_bounds__(256) void k_wcombo(const float* __restrict__ W_ih,
    const float* __restrict__ W_red, float* __restrict__ Wct) {
  __shared__ float As[16][68];
  __shared__ float Bs[16][68];
  int tid = threadIdx.x;
  int m0 = blockIdx.y*64, n0 = blockIdx.x*64;
  int rl = tid>>2, kq = (tid&3)*4;
  int kl = tid>>4, c4 = (tid&15)*4;
  int tx = tid&15, ty = tid>>4;
  float acc[4][4]={};
  for (int kk=0;kk<300;kk+=16){
    #pragma unroll
    for (int q=0;q<4;q++){
      int kg = kk+kq+q;
      As[kq+q][rl] = (kg<300) ? W_ih[(size_t)(m0+rl)*300 + kg] : 0.0f;
    }
    #pragma unroll
    for (int q=0;q<4;q++){
      int c = n0 + c4 + q;
      Bs[kl][c4+q] = (kk+kl<300 && c<812) ? W_red[(size_t)(kk+kl)*812 + c] : 0.0f;
    }
    __syncthreads();
    #pragma unroll
    for (int k=0;k<16;k++){
      const float* ap=&As[k][ty*4]; const float* bp=&Bs[k][tx*4];
      #pragma unroll
      for (int i=0;i<4;i++)
        #pragma unroll
        for (int j=0;j<4;j++) acc[i][j] += ap[i]*bp[j];
    }
    __syncthreads();
  }
  #pragma unroll
  for (int i=0;i<4;i++)
    #pragma unroll
    for (int j=0;j<4;j++){
      int row = m0+ty*4+i, col = n0+tx*4+j;
      if (col<812) Wct[(size_t)row*812 + col] = acc[i][j];
    }
}

// ---------------- G_emb[1024][2048] = emb[1024x300] @ Wct[:,0:300]^T + b_combo --------
__global__ __launch_bounds__(256) void k_gemb(const float* __restrict__ trg,
    const float* __restrict__ Wct, const float* __restrict__ bcomb,
    float* __restrict__ Gemb) {
  __shared__ float As[16][68];
  __shared__ float Bs[16][68];
  int tid = threadIdx.x;
  int m0 = blockIdx.y*64, n0 = blockIdx.x*64;
  int rl = tid>>2, kq = (tid&3)*4;
  int tx = tid&15, ty = tid>>4;
  float acc[4][4]={};
  int r = m0 + rl;
  const float* arow = trg + (size_t)(r&31)*9600 + (size_t)(r>>5)*300;
  for (int kk=0;kk<300;kk+=16){
    #pragma unroll
    for (int q=0;q<4;q++){
      int kg = kk+kq+q;
      As[kq+q][rl] = (kg<300) ? arow[kg] : 0.0f;
      Bs[kq+q][rl] = (kg<300) ? Wct[(size_t)(n0+rl)*812 + kg] : 0.0f;
    }
    __syncthreads();
    #pragma unroll
    for (int k=0;k<16;k++){
      const float* ap=&As[k][ty*4]; const float* bp=&Bs[k][tx*4];
      #pragma unroll
      for (int i=0;i<4;i++)
        #pragma unroll
        for (int j=0;j<4;j++) acc[i][j] += ap[i]*bp[j];
    }
    __syncthreads();
  }
  #pragma unroll
  for (int i=0;i<4;i++)
    #pragma unroll
    for (int j=0;j<4;j++){
      int rr = m0+ty*4+i, col = n0+tx*4+j;
      Gemb[(size_t)rr*2048 + col] = acc[i][j] + bcomb[col];
    }
}

// ---------------- Wg[1024][2048]: k<512 -> Wct[:,300+k]^T ; k>=512 -> W_hh^T ----------
__global__ __launch_bounds__(256) void k_wgpack(const float* __restrict__ Wct,
    const float* __restrict__ W_hh, float* __restrict__ Wg) {
  int idx = blockIdx.x*256 + threadIdx.x;
  if (idx >= 1024*2048) return;
  int k = idx >> 11, j = idx & 2047;
  Wg[idx] = (k < 512) ? Wct[(size_t)j*812 + 300 + k] : W_hh[(size_t)j*512 + (k-512)];
}

// ---------------- memories = enc @ W_enc^T + b_enc ----------------
__global__ __launch_bounds__(256) void k_memories(const float* __restrict__ A,
    const float* __restrict__ Bw, const float* __restrict__ bias,
    float* __restrict__ mem) {
  __shared__ float As[16][68];
  __shared__ float Bs[16][68];
  int tid = threadIdx.x;
  int m0 = blockIdx.y*64, n0 = blockIdx.x*64;
  int rl = tid>>2, kq = (tid&3)*4;
  int tx = tid&15, ty = tid>>4;
  float acc[4][4]={};
  for (int kk=0;kk<512;kk+=16){
    float4 av = *(const float4*)(A  + (size_t)(m0+rl)*512 + kk+kq);
    float4 bv = *(const float4*)(Bw + (size_t)(n0+rl)*512 + kk+kq);
    As[kq+0][rl]=av.x; As[kq+1][rl]=av.y; As[kq+2][rl]=av.z; As[kq+3][rl]=av.w;
    Bs[kq+0][rl]=bv.x; Bs[kq+1][rl]=bv.y; Bs[kq+2][rl]=bv.z; Bs[kq+3][rl]=bv.w;
    __syncthreads();
    #pragma unroll
    for (int k=0;k<16;k++){
      const float* ap=&As[k][ty*4]; const float* bp=&Bs[k][tx*4];
      #pragma unroll
      for (int i=0;i<4;i++)
        #pragma unroll
        for (int j=0;j<4;j++) acc[i][j] += ap[i]*bp[j];
    }
    __syncthreads();
  }
  #pragma unroll
  for (int i=0;i<4;i++){
    int n = m0+ty*4+i;
    #pragma unroll
    for (int j=0;j<4;j++){
      int h = n0+tx*4+j;
      mem[(size_t)n*512 + h] = acc[i][j] + bias[h];
    }
  }
}

// ---------------- W_log -> bf16 ----------------
__global__ __launch_bounds__(256) void k_wlogconv(const float* __restrict__ W_log,
    __hip_bfloat16* __restrict__ wlb) {
  int i4 = blockIdx.x*256 + threadIdx.x;
  if (i4 >= 32000*512/4) return;
  const float4 v = *(const float4*)(W_log + (size_t)i4*4);
  size_t o = (size_t)i4*4;
  wlb[o+0] = __float2bfloat16(v.x); wlb[o+1] = __float2bfloat16(v.y);
  wlb[o+2] = __float2bfloat16(v.z); wlb[o+3] = __float2bfloat16(v.w);
}

// ---------------- two-level grid barrier (agent scope, sequence epochs) ----------------
// bar layout (uints): grp cnt at g*32 (g<16); grp seq at 512+g*32; root cnt at 1024;
// root seq at 1056. Zeroed by k_init each launch; epochs increase monotonically.
__device__ __forceinline__ void grid_barrier(unsigned* bar, int blk, int epoch) {
  __syncthreads();
  if (threadIdx.x == 0) {
    __threadfence();
    int g = blk >> 4;
    unsigned tgt = (unsigned)(16*epoch);
    unsigned old = __hip_atomic_fetch_add(&bar[g*32], 1u, __ATOMIC_ACQ_REL, __HIP_MEMORY_SCOPE_AGENT);
    if (old + 1u == tgt) {               // last arriver of this group, this epoch
      unsigned r = __hip_atomic_fetch_add(&bar[1024], 1u, __ATOMIC_ACQ_REL, __HIP_MEMORY_SCOPE_AGENT);
      if (r + 1u == tgt) {               // last group overall
        __hip_atomic_store(&bar[1056], (unsigned)epoch, __ATOMIC_RELEASE, __HIP_MEMORY_SCOPE_AGENT);
      } else {
        while (__hip_atomic_load(&bar[1056], __ATOMIC_ACQUIRE, __HIP_MEMORY_SCOPE_AGENT) < (unsigned)epoch)
          __builtin_amdgcn_s_sleep(2);
      }
      __hip_atomic_store(&bar[512 + g*32], (unsigned)epoch, __ATOMIC_RELEASE, __HIP_MEMORY_SCOPE_AGENT);
    } else {
      while (__hip_atomic_load(&bar[512 + g*32], __ATOMIC_ACQUIRE, __HIP_MEMORY_SCOPE_AGENT) < (unsigned)epoch)
        __builtin_amdgcn_s_sleep(2);
    }
    __threadfence();
  }
  __syncthreads();
}

// ---------------- persistent 32-step decoder loop ----------------
// grid = 256 blocks x 256 threads, all co-resident.
// Phase G (all blocks): ks = blk>>4 (64 k each), rc = blk&15 (128 rows each):
//   part[ks*32+b][row] = sum_{k in slice} y[b][k] * Wg[k][row]
// Phase ES (32 blocks, blk = b*8+(b&7)): sum partials + Gemb -> LSTM -> energy ->
//   softmax -> ctx -> outputs.
__global__ __launch_bounds__(256) void k_loop(
    const float* __restrict__ Wg, const float* __restrict__ Gemb,
    const float* __restrict__ mem, const int* __restrict__ emask,
    float* __restrict__ c0, float* __restrict__ c1,
    float* __restrict__ hbuf, float* __restrict__ ctxb,
    float* __restrict__ hall, float* __restrict__ ctxa,
    float* __restrict__ cov, float* __restrict__ part,
    float* __restrict__ out, unsigned* __restrict__ bar) {
  __shared__ float ys[32][68];
  __shared__ float hl[512];
  __shared__ float es_s[400];
  __shared__ float ps_s[400];
  __shared__ float red[8];

  int blk = blockIdx.x, tid = threadIdx.x;
  int lane = tid & 63, w = tid >> 6;
  int ks = blk >> 4, rc = blk & 15;
  int bb = blk >> 3;
  bool es_active = (blk == bb*8 + (bb & 7));

  // phase-G thread mapping
  int tr = tid & 31, bg = tid >> 5;
  int row0 = rc*128 + tr*4;
  const float* wp = Wg + (size_t)(ks*64)*2048 + row0;
  int sb_l = tid >> 3, skq0 = (tid & 7) * 8;

  for (int t=0; t<32; t++){
    // ================= phase G =================
    {
      const float* side = (ks < 8) ? ctxb : hbuf;
      const float* src = side + (size_t)sb_l*512 + (ks&7)*64 + skq0;
      float4 s0 = *(const float4*)(src);
      float4 s1 = *(const float4*)(src+4);
      *(float4*)&ys[sb_l][skq0]   = s0;
      *(float4*)&ys[sb_l][skq0+4] = s1;
      __syncthreads();
      float acc[4][4] = {};
      #pragma unroll 4
      for (int k4=0;k4<16;k4++){
        float4 wk0 = *(const float4*)(wp + (size_t)(k4*4+0)*2048);
        float4 wk1 = *(const float4*)(wp + (size_t)(k4*4+1)*2048);
        float4 wk2 = *(const float4*)(wp + (size_t)(k4*4+2)*2048);
        float4 wk3 = *(const float4*)(wp + (size_t)(k4*4+3)*2048);
        #pragma unroll
        for (int j=0;j<4;j++){
          float4 y = *(const float4*)&ys[bg*4+j][k4*4];
          acc[0][j] += wk0.x*y.x + wk1.x*y.y + wk2.x*y.z + wk3.x*y.w;
          acc[1][j] += wk0.y*y.x + wk1.y*y.y + wk2.y*y.z + wk3.y*y.w;
          acc[2][j] += wk0.z*y.x + wk1.z*y.y + wk2.z*y.z + wk3.z*y.w;
          acc[3][j] += wk0.w*y.x + wk1.w*y.y + wk2.w*y.z + wk3.w*y.w;
        }
      }
      #pragma unroll
      for (int j=0;j<4;j++){
        float4 o; o.x=acc[0][j]; o.y=acc[1][j]; o.z=acc[2][j]; o.w=acc[3][j];
        *(float4*)(part + (size_t)(ks*32 + bg*4 + j)*2048 + row0) = o;
      }
      __syncthreads();   // protect ys before next use / barrier
    }
    grid_barrier(bar, blk, 2*t+1);

    // ================= phase ES =================
    if (es_active) {
      int r = t*32 + bb;
      const float* ci = (t&1) ? c1 : c0;
      float* co       = (t&1) ? c0 : c1;
      const float* gp = Gemb + (size_t)r*2048;
      // --- gates reduce + LSTM ---
      #pragma unroll
      for (int jj=0; jj<2; jj++){
        int j = tid + jj*256;
        float g[4];
        #pragma unroll
        for (int gi=0; gi<4; gi++){
          int row = gi*512 + j;
          float v = gp[row];
          #pragma unroll
          for (int k2=0; k2<16; k2++)
            v += part[(size_t)((k2<<5) + bb)*2048 + row];
          g[gi] = v;
        }
        float cp = ci[bb*512+j];
        float cn = sigf(g[1])*cp + sigf(g[0])*tanhf(g[2]);
        float hn = sigf(g[3])*tanhf(cn);
        co[bb*512+j] = cn;
        hbuf[bb*512+j] = hn;
        hall[(size_t)r*512+j] = hn;
        hl[j] = hn;
      }
      __syncthreads();
      // --- energy: wave w handles s in [w*100, w*100+100) ---
      {
        float4 h0 = *(const float4*)&hl[lane*8];
        float4 h1 = *(const float4*)&hl[lane*8+4];
        const float* mb = mem + (size_t)bb*204800;
        const int* em = emask + bb*400;
        for (int i=0;i<100;i+=2){
          int s0 = w*100 + i;
          const float4* mp0 = (const float4*)(mb + (size_t)s0*512 + lane*8);
          const float4* mp1 = (const float4*)(mb + (size_t)(s0+1)*512 + lane*8);
          float4 a0 = mp0[0], a1 = mp0[1];
          float4 b0 = mp1[0], b1 = mp1[1];
          float acc0 = h0.x*a0.x + h0.y*a0.y + h0.z*a0.z + h0.w*a0.w
                     + h1.x*a1.x + h1.y*a1.y + h1.z*a1.z + h1.w*a1.w;
          float acc1 = h0.x*b0.x + h0.y*b0.y + h0.z*b0.z + h0.w*b0.w
                     + h1.x*b1.x + h1.y*b1.y + h1.z*b1.z + h1.w*b1.w;
          #pragma unroll
          for (int off=32; off; off>>=1){
            acc0 += __shfl_xor(acc0, off);
            acc1 += __shfl_xor(acc1, off);
          }
          if (lane==0){
            float e0 = (em[s0]==0)   ? -INF_F : acc0;
            float e1 = (em[s0+1]==0) ? -INF_F : acc1;
            es_s[s0] = e0; es_s[s0+1] = e1;
            out[OFF_E + (size_t)r*400 + s0]   = e0;
            out[OFF_E + (size_t)r*400 + s0+1] = e1;
          }
        }
      }
      __syncthreads();
      // --- softmax ---
      {
        float e0 = es_s[tid];
        float e1 = (tid<144) ? es_s[tid+256] : -3.4e38f;
        float lm = fmaxf(e0,e1);
        #pragma unroll
        for (int off=32; off; off>>=1) lm = fmaxf(lm, __shfl_xor(lm, off));
        if (lane==0) red[w] = lm;
        __syncthreads();
        float m = fmaxf(fmaxf(red[0],red[1]), fmaxf(red[2],red[3]));
        float pv0 = expf(e0 - m);
        float pv1 = (tid<144) ? expf(e1 - m) : 0.0f;
        float sv = pv0 + pv1;
        #pragma unroll
        for (int off=32; off; off>>=1) sv += __shfl_xor(sv, off);
        if (lane==0) red[4+w] = sv;
        __syncthreads();
        float inv = 1.0f/(red[4]+red[5]+red[6]+red[7]);
        float a0 = pv0*inv;
        ps_s[tid] = a0;
        out[OFF_A + (size_t)r*400 + tid] = a0;
        float cv0 = cov[bb*400+tid];
        out[OFF_C + (size_t)r*400 + tid] = cv0;
        cov[bb*400+tid] = cv0 + a0;
        if (tid < 144){
          float a1 = pv1*inv;
          ps_s[tid+256] = a1;
          out[OFF_A + (size_t)r*400 + tid+256] = a1;
          float cv1 = cov[bb*400+tid+256];
          out[OFF_C + (size_t)r*400 + tid+256] = cv1;
          cov[bb*400+tid+256] = cv1 + a1;
        }
      }
      __syncthreads();
      // --- ctx ---
      #pragma unroll
      for (int hh=0; hh<2; hh++){
        int h = tid + hh*256;
        const float* mq = mem + (size_t)bb*204800 + h;
        float acc = 0.0f;
        #pragma unroll 8
        for (int s=0;s<400;s++) acc += ps_s[s]*mq[(size_t)s*512];
        ctxb[bb*512+h] = acc;
        ctxa[(size_t)r*512+h] = acc;
      }
    }
    grid_barrier(bar, blk, 2*t+2);
  }
}

// ---------------- logit_in = tanh([h_all|ctx_all]@W_cat^T + b_cat) -> bf16 ----------
__global__ __launch_bounds__(256) void k_logitin(const float* __restrict__ hall,
    const float* __restrict__ ctxa, const float* __restrict__ W_cat,
    const float* __restrict__ b_cat, __hip_bfloat16* __restrict__ lib) {
  __shared__ float As[16][68];
  __shared__ float Bs[16][68];
  int tid = threadIdx.x;
  int m0 = blockIdx.y*64, n0 = blockIdx.x*64;
  int rl = tid>>2, kq = (tid&3)*4;
  int tx = tid&15, ty = tid>>4;
  float acc[4][4]={};
  for (int kk=0;kk<1024;kk+=16){
    int kg = kk+kq;
    const float* asrc = (kg<512) ? (hall + (size_t)(m0+rl)*512 + kg)
                                 : (ctxa + (size_t)(m0+rl)*512 + kg - 512);
    float4 av = *(const float4*)asrc;
    float4 bv = *(const float4*)(W_cat + (size_t)(n0+rl)*1024 + kg);
    As[kq+0][rl]=av.x; As[kq+1][rl]=av.y; As[kq+2][rl]=av.z; As[kq+3][rl]=av.w;
    Bs[kq+0][rl]=bv.x; Bs[kq+1][rl]=bv.y; Bs[kq+2][rl]=bv.z; Bs[kq+3][rl]=bv.w;
    __syncthreads();
    #pragma unroll
    for (int k=0;k<16;k++){
      const float* ap=&As[k][ty*4]; const float* bp=&Bs[k][tx*4];
      #pragma unroll
      for (int i=0;i<4;i++)
        #pragma unroll
        for (int j=0;j<4;j++) acc[i][j] += ap[i]*bp[j];
    }
    __syncthreads();
  }
  #pragma unroll
  for (int i=0;i<4;i++)
    #pragma unroll
    for (int j=0;j<4;j++){
      int rr = m0+ty*4+i, col = n0+tx*4+j;
      float v = tanhf(acc[i][j] + b_cat[col]);
      lib[(size_t)rr*512 + col] = __float2bfloat16(v);
    }
}

// swizzled LDS byte offset: row in [0,128), slot in [0,4) (16B granules of a 64B row)
__device__ __forceinline__ int lds_off(int row, int slot) {
  return (row<<6) + (((slot ^ ((row>>1)&3))&3)<<4);
}

// ---------------- logits = logit_in @ W_log^T + b_log (bf16 MFMA, 128x128 tile) -------
__global__ __launch_bounds__(256) void k_logits(const __hip_bfloat16* __restrict__ Ab,
    const __hip_bfloat16* __restrict__ Wb, const float* __restrict__ b_log,
    float* __restrict__ out) {
  __shared__ short As[4096];
  __shared__ short Bs[4096];
  int tid = threadIdx.x;
  int m0 = blockIdx.x*128, n0 = blockIdx.y*128;
  int w = tid>>6, lane = tid&63;
  int wr = w>>1, wc = w&1;
  int lr = lane&15, kg2 = lane>>4;
  const short* A = (const short*)Ab;
  const short* W = (const short*)Wb;

  int srow = tid>>1;
  int ss   = (tid&1)*2;
  const short* ga = A + (size_t)(m0+srow)*512 + ss*8;
  const short* gw = W + (size_t)(n0+srow)*512 + ss*8;
  int wo0 = lds_off(srow, ss), wo1 = lds_off(srow, ss+1);

  int raoff[4], rboff[4];
  #pragma unroll
  for (int q=0;q<4;q++){
    raoff[q] = lds_off(wr*64 + q*16 + lr, kg2);
    rboff[q] = lds_off(wc*64 + q*16 + lr, kg2);
  }

  facc4 acc[4][4] = {};
  bfrag8 ra0 = *(const bfrag8*)(ga);
  bfrag8 ra1 = *(const bfrag8*)(ga+8);
  bfrag8 rb0 = *(const bfrag8*)(gw);
  bfrag8 rb1 = *(const bfrag8*)(gw+8);

  for (int i=0;i<16;i++){
    __syncthreads();
    *(bfrag8*)((char*)As + wo0) = ra0;
    *(bfrag8*)((char*)As + wo1) = ra1;
    *(bfrag8*)((char*)Bs + wo0) = rb0;
    *(bfrag8*)((char*)Bs + wo1) = rb1;
    __syncthreads();
    if (i<15){
      ga += 32; gw += 32;
      ra0 = *(const bfrag8*)(ga);
      ra1 = *(const bfrag8*)(ga+8);
      rb0 = *(const bfrag8*)(gw);
      rb1 = *(const bfrag8*)(gw+8);
    }
    bfrag8 af[4], bf[4];
    #pragma unroll
    for (int q=0;q<4;q++){
      af[q] = *(const bfrag8*)((char*)As + raoff[q]);
      bf[q] = *(const bfrag8*)((char*)Bs + rboff[q]);
    }
    #pragma unroll
    for (int mi=0;mi<4;mi++)
      #pragma unroll
      for (int ni=0;ni<4;ni++)
        acc[mi][ni] = __builtin_amdgcn_mfma_f32_16x16x32_bf16(af[mi], bf[ni], acc[mi][ni], 0,0,0);
  }

  #pragma unroll
  for (int mi=0;mi<4;mi++){
    int row = m0 + wr*64 + mi*16 + kg2*4;
    #pragma unroll
    for (int ni=0;ni<4;ni++){
      int col = n0 + wc*64 + ni*16 + lr;
      float bl = b_log[col];
      #pragma unroll
      for (int q=0;q<4;q++){
        float v = acc[mi][ni][q] + bl;
        out[(size_t)(row+q)*32050 + col] = (v == 0.0f) ? -INF_F : v;
      }
    }
  }
}

// ---------------- OOV region fill ----------------
__global__ __launch_bounds__(256) void k_oov(float* __restrict__ out) {
  int idx = blockIdx.x*256 + threadIdx.x;
  if (idx >= 1024*50) return;
  int rr = idx/50, v = 32000 + idx%50;
  out[(size_t)rr*32050 + v] = -INF_F;
}

// ---------------- scatter-max of energies into extended logits ----------------
__global__ __launch_bounds__(128) void k_scatter(const int* __restrict__ ext_src,
    float* __restrict__ out) {
  __shared__ int tok[400];
  __shared__ float ev[400];
  int rr = blockIdx.x;
  int b = rr & 31;
  int tid = threadIdx.x;
  for (int s=tid; s<400; s+=128){
    tok[s] = ext_src[b*400+s];
    ev[s]  = out[OFF_E + (size_t)rr*400 + s];
  }
  __syncthreads();
  for (int s=tid; s<400; s+=128){
    int tk = tok[s];
    float m = ev[s];
    bool first = true;
    for (int s2=0; s2<400; s2++){
      if (tok[s2]==tk){
        if (s2 < s) first=false;
        m = fmaxf(m, ev[s2]);
      }
    }
    if (first && m != -INF_F){
      size_t idx = (size_t)rr*32050 + tk;
      float wv = out[idx];
      float extv = (wv == -INF_F) ? 0.0f : wv;
      float nv = extv + m;
      out[idx] = (nv == 0.0f) ? -INF_F : nv;
    }
  }
}

extern "C" void kernel_launch(void* const* d_in, const int* in_sizes, int n_in,
                              void* d_out, int out_size, void* d_ws, size_t ws_size,
                              hipStream_t stream) {
  const float* trg   = (const float*)d_in[0];
  const int*   ext   = (const int*)  d_in[1];
  const float* inits = (const float*)d_in[2];
  const float* enc   = (const float*)d_in[3];
  const int*   emask = (const int*)  d_in[4];
  const float* W_enc = (const float*)d_in[5];
  const float* b_enc = (const float*)d_in[6];
  const float* W_red = (const float*)d_in[7];
  const float* b_red = (const float*)d_in[8];
  const float* W_ih  = (const float*)d_in[9];
  const float* W_hh  = (const float*)d_in[10];
  const float* b_ih  = (const float*)d_in[11];
  const float* b_hh  = (const float*)d_in[12];
  const float* W_cat = (const float*)d_in[13];
  const float* b_cat = (const float*)d_in[14];
  const float* W_log = (const float*)d_in[15];
  const float* b_log = (const float*)d_in[16];
  float* out = (float*)d_out;
  float* ws  = (float*)d_ws;

  float* mem   = ws + 0ull;          // 6,553,600
  float* Wg    = ws + 6553600ull;    // 2,097,152
  float* Wct   = ws + 8650752ull;    // 1,662,976
  float* Gemb  = ws + 10313728ull;   // 2,097,152
  float* bcomb = ws + 12410880ull;   // 2,048
  float* hbuf  = ws + 12412928ull;   // 16,384
  float* c0    = ws + 12429312ull;   // 16,384
  float* c1    = ws + 12445696ull;   // 16,384
  float* ctxb  = ws + 12462080ull;   // 16,384
  float* hall  = ws + 12478464ull;   // 524,288
  float* ctxa  = ws + 13002752ull;   // 524,288
  float* cov   = ws + 13527040ull;   // 12,800
  float* part  = ws + 13539840ull;   // 1,048,576
  unsigned* bar = (unsigned*)(ws + 14588416ull);               // 2,048 uints
  __hip_bfloat16* lib = (__hip_bfloat16*)(ws + 14590464ull);   // 262,144 floats
  __hip_bfloat16* wlb = (__hip_bfloat16*)(ws + 14852608ull);   // 8,192,000 floats

  k_init<<<64,256,0,stream>>>(inits, hbuf, c0, ctxb, cov, bar);
  k_bcombo<<<8,256,0,stream>>>(W_ih, b_red, b_ih, b_hh, bcomb);
  k_wcombo<<<dim3(13,32),256,0,stream>>>(W_ih, W_red, Wct);
  k_gemb<<<dim3(32,16),256,0,stream>>>(trg, Wct, bcomb, Gemb);
  k_wgpack<<<8192,256,0,stream>>>(Wct, W_hh, Wg);
  k_memories<<<dim3(8,200),256,0,stream>>>(enc, W_enc, b_enc, mem);
  k_wlogconv<<<16000,256,0,stream>>>(W_log, wlb);

  k_loop<<<256,256,0,stream>>>(Wg, Gemb, mem, emask, c0, c1, hbuf, ctxb,
                               hall, ctxa, cov, part, out, bar);

  k_logitin<<<dim3(8,16),256,0,stream>>>(hall, ctxa, W_cat, b_cat, lib);
  k_logits<<<dim3(8,250),256,0,stream>>>(lib, wlb, b_log, out);
  k_oov<<<200,256,0,stream>>>(out);
  k_scatter<<<1024,128,0,stream>>>(ext, out);
}

// Round 5
// 1568.210 us; speedup vs baseline: 9.7701x; 9.7701x over previous
//
#include <hip/hip_runtime.h>
#include <hip/hip_bf16.h>

#define INF_F 1000000000000.0f

typedef __attribute__((ext_vector_type(8))) short bfrag8;
typedef __attribute__((ext_vector_type(4))) float facc4;

__device__ __forceinline__ float sigf(float x){ return 1.0f/(1.0f + expf(-x)); }

// out-region offsets (floats)
#define OFF_LOG 0ull
#define OFF_A   32819200ull
#define OFF_C   33228800ull
#define OFF_E   33638400ull

// ---------------- init ----------------
__global__ __launch_bounds__(256) void k_init(const float* __restrict__ init_s,
    float* __restrict__ hbuf, float* __restrict__ c0, float* __restrict__ ctxb,
    float* __restrict__ cov) {
  int i = blockIdx.x*256 + threadIdx.x;
  if (i < 32*512) { float v = init_s[i]; hbuf[i]=v; c0[i]=v; ctxb[i]=0.0f; }
  if (i < 32*400) cov[i] = 0.0f;
}

// ---------------- b_combo = W_ih@b_red + b_ih + b_hh ----------------
__global__ __launch_bounds__(256) void k_bcombo(const float* __restrict__ W_ih,
    const float* __restrict__ b_red, const float* __restrict__ b_ih,
    const float* __restrict__ b_hh, float* __restrict__ bcomb) {
  int j = blockIdx.x*256 + threadIdx.x;
  if (j >= 2048) return;
  float acc = b_ih[j] + b_hh[j];
  for (int m=0;m<300;m++) acc += W_ih[j*300+m]*b_red[m];
  bcomb[j] = acc;
}

// ---------------- Wct[2048][812] = W_ih[2048x300] @ W_red[300x812] ----------------
__global__ __launch_bounds__(256) void k_wcombo(const float* __restrict__ W_ih,
    const float* __restrict__ W_red, float* __restrict__ Wct) {
  __shared__ float As[16][68];
  __shared__ float Bs[16][68];
  int tid = threadIdx.x;
  int m0 = blockIdx.y*64, n0 = blockIdx.x*64;
  int rl = tid>>2, kq = (tid&3)*4;
  int kl = tid>>4, c4 = (tid&15)*4;
  int tx = tid&15, ty = tid>>4;
  float acc[4][4]={};
  for (int kk=0;kk<300;kk+=16){
    #pragma unroll
    for (int q=0;q<4;q++){
      int kg = kk+kq+q;
      As[kq+q][rl] = (kg<300) ? W_ih[(size_t)(m0+rl)*300 + kg] : 0.0f;
    }
    #pragma unroll
    for (int q=0;q<4;q++){
      int c = n0 + c4 + q;
      Bs[kl][c4+q] = (kk+kl<300 && c<812) ? W_red[(size_t)(kk+kl)*812 + c] : 0.0f;
    }
    __syncthreads();
    #pragma unroll
    for (int k=0;k<16;k++){
      const float* ap=&As[k][ty*4]; const float* bp=&Bs[k][tx*4];
      #pragma unroll
      for (int i=0;i<4;i++)
        #pragma unroll
        for (int j=0;j<4;j++) acc[i][j] += ap[i]*bp[j];
    }
    __syncthreads();
  }
  #pragma unroll
  for (int i=0;i<4;i++)
    #pragma unroll
    for (int j=0;j<4;j++){
      int row = m0+ty*4+i, col = n0+tx*4+j;
      if (col<812) Wct[(size_t)row*812 + col] = acc[i][j];
    }
}

// ---------------- G_emb[1024][2048] = emb[1024x300] @ Wct[:,0:300]^T + b_combo --------
__global__ __launch_bounds__(256) void k_gemb(const float* __restrict__ trg,
    const float* __restrict__ Wct, const float* __restrict__ bcomb,
    float* __restrict__ Gemb) {
  __shared__ float As[16][68];
  __shared__ float Bs[16][68];
  int tid = threadIdx.x;
  int m0 = blockIdx.y*64, n0 = blockIdx.x*64;
  int rl = tid>>2, kq = (tid&3)*4;
  int tx = tid&15, ty = tid>>4;
  float acc[4][4]={};
  int r = m0 + rl;
  const float* arow = trg + (size_t)(r&31)*9600 + (size_t)(r>>5)*300;
  for (int kk=0;kk<300;kk+=16){
    #pragma unroll
    for (int q=0;q<4;q++){
      int kg = kk+kq+q;
      As[kq+q][rl] = (kg<300) ? arow[kg] : 0.0f;
      Bs[kq+q][rl] = (kg<300) ? Wct[(size_t)(n0+rl)*812 + kg] : 0.0f;
    }
    __syncthreads();
    #pragma unroll
    for (int k=0;k<16;k++){
      const float* ap=&As[k][ty*4]; const float* bp=&Bs[k][tx*4];
      #pragma unroll
      for (int i=0;i<4;i++)
        #pragma unroll
        for (int j=0;j<4;j++) acc[i][j] += ap[i]*bp[j];
    }
    __syncthreads();
  }
  #pragma unroll
  for (int i=0;i<4;i++)
    #pragma unroll
    for (int j=0;j<4;j++){
      int rr = m0+ty*4+i, col = n0+tx*4+j;
      Gemb[(size_t)rr*2048 + col] = acc[i][j] + bcomb[col];
    }
}

// ---------------- Wg[1024][2048]: k<512 -> Wct[:,300+k]^T ; k>=512 -> W_hh^T ----------
__global__ __launch_bounds__(256) void k_wgpack(const float* __restrict__ Wct,
    const float* __restrict__ W_hh, float* __restrict__ Wg) {
  int idx = blockIdx.x*256 + threadIdx.x;
  if (idx >= 1024*2048) return;
  int k = idx >> 11, j = idx & 2047;
  Wg[idx] = (k < 512) ? Wct[(size_t)j*812 + 300 + k] : W_hh[(size_t)j*512 + (k-512)];
}

// ---------------- memories = enc @ W_enc^T + b_enc ----------------
__global__ __launch_bounds__(256) void k_memories(const float* __restrict__ A,
    const float* __restrict__ Bw, const float* __restrict__ bias,
    float* __restrict__ mem) {
  __shared__ float As[16][68];
  __shared__ float Bs[16][68];
  int tid = threadIdx.x;
  int m0 = blockIdx.y*64, n0 = blockIdx.x*64;
  int rl = tid>>2, kq = (tid&3)*4;
  int tx = tid&15, ty = tid>>4;
  float acc[4][4]={};
  for (int kk=0;kk<512;kk+=16){
    float4 av = *(const float4*)(A  + (size_t)(m0+rl)*512 + kk+kq);
    float4 bv = *(const float4*)(Bw + (size_t)(n0+rl)*512 + kk+kq);
    As[kq+0][rl]=av.x; As[kq+1][rl]=av.y; As[kq+2][rl]=av.z; As[kq+3][rl]=av.w;
    Bs[kq+0][rl]=bv.x; Bs[kq+1][rl]=bv.y; Bs[kq+2][rl]=bv.z; Bs[kq+3][rl]=bv.w;
    __syncthreads();
    #pragma unroll
    for (int k=0;k<16;k++){
      const float* ap=&As[k][ty*4]; const float* bp=&Bs[k][tx*4];
      #pragma unroll
      for (int i=0;i<4;i++)
        #pragma unroll
        for (int j=0;j<4;j++) acc[i][j] += ap[i]*bp[j];
    }
    __syncthreads();
  }
  #pragma unroll
  for (int i=0;i<4;i++){
    int n = m0+ty*4+i;
    #pragma unroll
    for (int j=0;j<4;j++){
      int h = n0+tx*4+j;
      mem[(size_t)n*512 + h] = acc[i][j] + bias[h];
    }
  }
}

// ---------------- W_log -> bf16 ----------------
__global__ __launch_bounds__(256) void k_wlogconv(const float* __restrict__ W_log,
    __hip_bfloat16* __restrict__ wlb) {
  int i4 = blockIdx.x*256 + threadIdx.x;
  if (i4 >= 32000*512/4) return;
  const float4 v = *(const float4*)(W_log + (size_t)i4*4);
  size_t o = (size_t)i4*4;
  wlb[o+0] = __float2bfloat16(v.x); wlb[o+1] = __float2bfloat16(v.y);
  wlb[o+2] = __float2bfloat16(v.z); wlb[o+3] = __float2bfloat16(v.w);
}

// ---------------- per-step: gates partial GEMM ----------------
// grid (ks=8, rc=16); partial[ks*32+b][row] = sum_{k in ks chunk} yh[b][k]*Wg[k][row]
__global__ __launch_bounds__(256) void k_gates(const float* __restrict__ ctxb,
    const float* __restrict__ hbuf, const float* __restrict__ Wg,
    float* __restrict__ partials) {
  __shared__ float yh_s[128][32];
  int ks = blockIdx.x;
  int rc = blockIdx.y;
  int tid = threadIdx.x;
  const float* side = (ks < 4) ? ctxb : hbuf;
  int kbase = (ks & 3) * 128;
  {
    int b_l = tid >> 3, kq0 = (tid & 7) * 16;
    const float* src = side + (size_t)b_l*512 + kbase + kq0;
    #pragma unroll
    for (int q=0;q<16;q+=4){
      float4 v = *(const float4*)(src + q);
      yh_s[kq0+q+0][b_l]=v.x; yh_s[kq0+q+1][b_l]=v.y;
      yh_s[kq0+q+2][b_l]=v.z; yh_s[kq0+q+3][b_l]=v.w;
    }
  }
  __syncthreads();
  int tr = tid & 31, bg = tid >> 5;
  int row0 = rc*128 + tr*4;
  float acc[4][4] = {};
  const float* wp = Wg + (size_t)(ks*128)*2048 + row0;
  #pragma unroll 8
  for (int k=0;k<128;k++){
    float4 w = *(const float4*)(wp + (size_t)k*2048);
    float4 y = *(const float4*)&yh_s[k][bg*4];
    acc[0][0]+=w.x*y.x; acc[0][1]+=w.x*y.y; acc[0][2]+=w.x*y.z; acc[0][3]+=w.x*y.w;
    acc[1][0]+=w.y*y.x; acc[1][1]+=w.y*y.y; acc[1][2]+=w.y*y.z; acc[1][3]+=w.y*y.w;
    acc[2][0]+=w.z*y.x; acc[2][1]+=w.z*y.y; acc[2][2]+=w.z*y.z; acc[2][3]+=w.z*y.w;
    acc[3][0]+=w.w*y.x; acc[3][1]+=w.w*y.y; acc[3][2]+=w.w*y.z; acc[3][3]+=w.w*y.w;
  }
  #pragma unroll
  for (int j=0;j<4;j++){
    float4 o; o.x=acc[0][j]; o.y=acc[1][j]; o.z=acc[2][j]; o.w=acc[3][j];
    *(float4*)(partials + (size_t)(ks*32 + bg*4 + j)*2048 + row0) = o;
  }
}

// ---------------- per-step: partial reduce + LSTM (redundant) + energy chunk --------
// grid 256 linear blocks: b = blk&31, sc = blk>>5 (XCD = b%8 for mem locality)
__global__ __launch_bounds__(256) void k_lstm_energy(const float* __restrict__ part,
    const float* __restrict__ Gemb,
    const float* __restrict__ c_in, float* __restrict__ c_out,
    float* __restrict__ hbuf, float* __restrict__ hall,
    const float* __restrict__ mem, const int* __restrict__ emask,
    float* __restrict__ out, int t) {
  __shared__ float hl[512];
  int blk = blockIdx.x, tid = threadIdx.x;
  int b = blk & 31, sc = blk >> 5;
  int r = t*32 + b;
  int lane = tid & 63, w = tid >> 6;
  const float* gp = Gemb + (size_t)r*2048;
  #pragma unroll
  for (int jj=0; jj<2; jj++){
    int j = tid + jj*256;
    float g[4];
    #pragma unroll
    for (int gi=0; gi<4; gi++){
      int row = gi*512 + j;
      float v = gp[row];
      #pragma unroll
      for (int ks=0; ks<8; ks++)
        v += part[(size_t)(ks*32+b)*2048 + row];
      g[gi] = v;
    }
    float cp = c_in[b*512+j];
    float cn = sigf(g[1])*cp + sigf(g[0])*tanhf(g[2]);
    float hn = sigf(g[3])*tanhf(cn);
    hl[j] = hn;
    if (sc==0){
      c_out[b*512+j]=cn; hbuf[b*512+j]=hn; hall[(size_t)r*512+j]=hn;
    }
  }
  __syncthreads();
  float4 h0 = *(const float4*)&hl[lane*8];
  float4 h1 = *(const float4*)&hl[lane*8+4];
  const float* mb = mem + (size_t)b*204800;
  const int* em = emask + b*400;
  for (int i=0;i<13;i++){
    int s_l = i*4 + w;
    if (s_l < 50){
      int s = sc*50 + s_l;
      const float4* mp = (const float4*)(mb + (size_t)s*512 + lane*8);
      float4 m0 = mp[0], m1 = mp[1];
      float acc = h0.x*m0.x + h0.y*m0.y + h0.z*m0.z + h0.w*m0.w
                + h1.x*m1.x + h1.y*m1.y + h1.z*m1.z + h1.w*m1.w;
      #pragma unroll
      for (int off=32; off; off>>=1) acc += __shfl_xor(acc, off);
      if (lane==0){
        out[OFF_E + (size_t)r*400 + s] = (em[s]==0) ? -INF_F : acc;
      }
    }
  }
}

// ---------------- per-step: softmax (redundant) + ctx chunk + attn/cov -------------
// grid 128 linear blocks: b = blk&31, hc = blk>>5 (4 chunks x 128 h)
__global__ __launch_bounds__(256) void k_ctx(float* __restrict__ out,
    const float* __restrict__ mem, float* __restrict__ ctxb, float* __restrict__ ctxa,
    float* __restrict__ cov, int t) {
  __shared__ float ps[400];
  __shared__ float red[8];
  __shared__ float tmp[128];
  int blk = blockIdx.x, tid = threadIdx.x;
  int b = blk & 31, hc = blk >> 5;
  int r = t*32 + b;
  int lane = tid & 63, w = tid >> 6;
  float e0 = out[OFF_E + (size_t)r*400 + tid];
  float e1 = (tid < 144) ? out[OFF_E + (size_t)r*400 + tid + 256] : -3.4e38f;
  float lm = fmaxf(e0, e1);
  #pragma unroll
  for (int off=32; off; off>>=1) lm = fmaxf(lm, __shfl_xor(lm, off));
  if (lane==0) red[w] = lm;
  __syncthreads();
  float m = fmaxf(fmaxf(red[0],red[1]), fmaxf(red[2],red[3]));
  float pv0 = expf(e0 - m);
  float pv1 = (tid < 144) ? expf(e1 - m) : 0.0f;
  float sv = pv0 + pv1;
  #pragma unroll
  for (int off=32; off; off>>=1) sv += __shfl_xor(sv, off);
  if (lane==0) red[4+w] = sv;
  __syncthreads();
  float inv = 1.0f/(red[4]+red[5]+red[6]+red[7]);
  ps[tid] = pv0*inv;
  if (tid < 144) ps[tid+256] = pv1*inv;
  __syncthreads();
  // ctx chunk: 128 h, two s-halves
  int hloc = tid & 127, sh = tid >> 7;
  int h = hc*128 + hloc;
  const float* mq = mem + (size_t)b*204800 + h;
  float acc = 0.0f;
  {
    const float* mqs = mq + (size_t)sh*200*512;
    const float* pss = &ps[sh*200];
    #pragma unroll 8
    for (int s=0;s<200;s++) acc += pss[s]*mqs[(size_t)s*512];
  }
  if (sh==1) tmp[hloc] = acc;
  __syncthreads();
  if (sh==0){
    float v = acc + tmp[hloc];
    ctxb[b*512+h] = v;
    ctxa[(size_t)r*512+h] = v;
  }
  if (hc==0){
    for (int s=tid; s<400; s+=256){
      float a = ps[s];
      out[OFF_A + (size_t)r*400 + s] = a;
      float cv = cov[b*400+s];
      out[OFF_C + (size_t)r*400 + s] = cv;
      cov[b*400+s] = cv + a;
    }
  }
}

// ---------------- logit_in = tanh([h_all|ctx_all]@W_cat^T + b_cat) -> bf16 ----------
__global__ __launch_bounds__(256) void k_logitin(const float* __restrict__ hall,
    const float* __restrict__ ctxa, const float* __restrict__ W_cat,
    const float* __restrict__ b_cat, __hip_bfloat16* __restrict__ lib) {
  __shared__ float As[16][68];
  __shared__ float Bs[16][68];
  int tid = threadIdx.x;
  int m0 = blockIdx.y*64, n0 = blockIdx.x*64;
  int rl = tid>>2, kq = (tid&3)*4;
  int tx = tid&15, ty = tid>>4;
  float acc[4][4]={};
  for (int kk=0;kk<1024;kk+=16){
    int kg = kk+kq;
    const float* asrc = (kg<512) ? (hall + (size_t)(m0+rl)*512 + kg)
                                 : (ctxa + (size_t)(m0+rl)*512 + kg - 512);
    float4 av = *(const float4*)asrc;
    float4 bv = *(const float4*)(W_cat + (size_t)(n0+rl)*1024 + kg);
    As[kq+0][rl]=av.x; As[kq+1][rl]=av.y; As[kq+2][rl]=av.z; As[kq+3][rl]=av.w;
    Bs[kq+0][rl]=bv.x; Bs[kq+1][rl]=bv.y; Bs[kq+2][rl]=bv.z; Bs[kq+3][rl]=bv.w;
    __syncthreads();
    #pragma unroll
    for (int k=0;k<16;k++){
      const float* ap=&As[k][ty*4]; const float* bp=&Bs[k][tx*4];
      #pragma unroll
      for (int i=0;i<4;i++)
        #pragma unroll
        for (int j=0;j<4;j++) acc[i][j] += ap[i]*bp[j];
    }
    __syncthreads();
  }
  #pragma unroll
  for (int i=0;i<4;i++)
    #pragma unroll
    for (int j=0;j<4;j++){
      int rr = m0+ty*4+i, col = n0+tx*4+j;
      float v = tanhf(acc[i][j] + b_cat[col]);
      lib[(size_t)rr*512 + col] = __float2bfloat16(v);
    }
}

// swizzled LDS byte offset: row in [0,128), slot in [0,4) (16B granules of a 64B row)
__device__ __forceinline__ int lds_off(int row, int slot) {
  return (row<<6) + (((slot ^ ((row>>1)&3))&3)<<4);
}

// ---------------- logits = logit_in @ W_log^T + b_log (bf16 MFMA, 128x128 tile) -------
__global__ __launch_bounds__(256) void k_logits(const __hip_bfloat16* __restrict__ Ab,
    const __hip_bfloat16* __restrict__ Wb, const float* __restrict__ b_log,
    float* __restrict__ out) {
  __shared__ short As[4096];
  __shared__ short Bs[4096];
  int tid = threadIdx.x;
  int m0 = blockIdx.x*128, n0 = blockIdx.y*128;
  int w = tid>>6, lane = tid&63;
  int wr = w>>1, wc = w&1;
  int lr = lane&15, kg2 = lane>>4;
  const short* A = (const short*)Ab;
  const short* W = (const short*)Wb;

  int srow = tid>>1;
  int ss   = (tid&1)*2;
  const short* ga = A + (size_t)(m0+srow)*512 + ss*8;
  const short* gw = W + (size_t)(n0+srow)*512 + ss*8;
  int wo0 = lds_off(srow, ss), wo1 = lds_off(srow, ss+1);

  int raoff[4], rboff[4];
  #pragma unroll
  for (int q=0;q<4;q++){
    raoff[q] = lds_off(wr*64 + q*16 + lr, kg2);
    rboff[q] = lds_off(wc*64 + q*16 + lr, kg2);
  }

  facc4 acc[4][4] = {};
  bfrag8 ra0 = *(const bfrag8*)(ga);
  bfrag8 ra1 = *(const bfrag8*)(ga+8);
  bfrag8 rb0 = *(const bfrag8*)(gw);
  bfrag8 rb1 = *(const bfrag8*)(gw+8);

  for (int i=0;i<16;i++){
    __syncthreads();
    *(bfrag8*)((char*)As + wo0) = ra0;
    *(bfrag8*)((char*)As + wo1) = ra1;
    *(bfrag8*)((char*)Bs + wo0) = rb0;
    *(bfrag8*)((char*)Bs + wo1) = rb1;
    __syncthreads();
    if (i<15){
      ga += 32; gw += 32;
      ra0 = *(const bfrag8*)(ga);
      ra1 = *(const bfrag8*)(ga+8);
      rb0 = *(const bfrag8*)(gw);
      rb1 = *(const bfrag8*)(gw+8);
    }
    bfrag8 af[4], bf[4];
    #pragma unroll
    for (int q=0;q<4;q++){
      af[q] = *(const bfrag8*)((char*)As + raoff[q]);
      bf[q] = *(const bfrag8*)((char*)Bs + rboff[q]);
    }
    #pragma unroll
    for (int mi=0;mi<4;mi++)
      #pragma unroll
      for (int ni=0;ni<4;ni++)
        acc[mi][ni] = __builtin_amdgcn_mfma_f32_16x16x32_bf16(af[mi], bf[ni], acc[mi][ni], 0,0,0);
  }

  #pragma unroll
  for (int mi=0;mi<4;mi++){
    int row = m0 + wr*64 + mi*16 + kg2*4;
    #pragma unroll
    for (int ni=0;ni<4;ni++){
      int col = n0 + wc*64 + ni*16 + lr;
      float bl = b_log[col];
      #pragma unroll
      for (int q=0;q<4;q++){
        float v = acc[mi][ni][q] + bl;
        out[(size_t)(row+q)*32050 + col] = (v == 0.0f) ? -INF_F : v;
      }
    }
  }
}

// ---------------- OOV region fill ----------------
__global__ __launch_bounds__(256) void k_oov(float* __restrict__ out) {
  int idx = blockIdx.x*256 + threadIdx.x;
  if (idx >= 1024*50) return;
  int rr = idx/50, v = 32000 + idx%50;
  out[(size_t)rr*32050 + v] = -INF_F;
}

// ---------------- scatter-max of energies into extended logits ----------------
__global__ __launch_bounds__(128) void k_scatter(const int* __restrict__ ext_src,
    float* __restrict__ out) {
  __shared__ int tok[400];
  __shared__ float ev[400];
  int rr = blockIdx.x;
  int b = rr & 31;
  int tid = threadIdx.x;
  for (int s=tid; s<400; s+=128){
    tok[s] = ext_src[b*400+s];
    ev[s]  = out[OFF_E + (size_t)rr*400 + s];
  }
  __syncthreads();
  for (int s=tid; s<400; s+=128){
    int tk = tok[s];
    float m = ev[s];
    bool first = true;
    for (int s2=0; s2<400; s2++){
      if (tok[s2]==tk){
        if (s2 < s) first=false;
        m = fmaxf(m, ev[s2]);
      }
    }
    if (first && m != -INF_F){
      size_t idx = (size_t)rr*32050 + tk;
      float wv = out[idx];
      float extv = (wv == -INF_F) ? 0.0f : wv;
      float nv = extv + m;
      out[idx] = (nv == 0.0f) ? -INF_F : nv;
    }
  }
}

extern "C" void kernel_launch(void* const* d_in, const int* in_sizes, int n_in,
                              void* d_out, int out_size, void* d_ws, size_t ws_size,
                              hipStream_t stream) {
  const float* trg   = (const float*)d_in[0];
  const int*   ext   = (const int*)  d_in[1];
  const float* inits = (const float*)d_in[2];
  const float* enc   = (const float*)d_in[3];
  const int*   emask = (const int*)  d_in[4];
  const float* W_enc = (const float*)d_in[5];
  const float* b_enc = (const float*)d_in[6];
  const float* W_red = (const float*)d_in[7];
  const float* b_red = (const float*)d_in[8];
  const float* W_ih  = (const float*)d_in[9];
  const float* W_hh  = (const float*)d_in[10];
  const float* b_ih  = (const float*)d_in[11];
  const float* b_hh  = (const float*)d_in[12];
  const float* W_cat = (const float*)d_in[13];
  const float* b_cat = (const float*)d_in[14];
  const float* W_log = (const float*)d_in[15];
  const float* b_log = (const float*)d_in[16];
  float* out = (float*)d_out;
  float* ws  = (float*)d_ws;

  float* mem   = ws + 0ull;          // 6,553,600
  float* Wg    = ws + 6553600ull;    // 2,097,152
  float* Wct   = ws + 8650752ull;    // 1,662,976
  float* Gemb  = ws + 10313728ull;   // 2,097,152
  float* bcomb = ws + 12410880ull;   // 2,048
  float* hbuf  = ws + 12412928ull;   // 16,384
  float* c0    = ws + 12429312ull;   // 16,384
  float* c1    = ws + 12445696ull;   // 16,384
  float* ctxb  = ws + 12462080ull;   // 16,384
  float* hall  = ws + 12478464ull;   // 524,288
  float* ctxa  = ws + 13002752ull;   // 524,288
  float* cov   = ws + 13527040ull;   // 12,800
  float* part  = ws + 13539840ull;   // 524,288
  __hip_bfloat16* lib = (__hip_bfloat16*)(ws + 14590464ull);   // 262,144 floats
  __hip_bfloat16* wlb = (__hip_bfloat16*)(ws + 14852608ull);   // 8,192,000 floats

  k_init<<<64,256,0,stream>>>(inits, hbuf, c0, ctxb, cov);
  k_bcombo<<<8,256,0,stream>>>(W_ih, b_red, b_ih, b_hh, bcomb);
  k_wcombo<<<dim3(13,32),256,0,stream>>>(W_ih, W_red, Wct);
  k_gemb<<<dim3(32,16),256,0,stream>>>(trg, Wct, bcomb, Gemb);
  k_wgpack<<<8192,256,0,stream>>>(Wct, W_hh, Wg);
  k_memories<<<dim3(8,200),256,0,stream>>>(enc, W_enc, b_enc, mem);
  k_wlogconv<<<16000,256,0,stream>>>(W_log, wlb);

  for (int t=0;t<32;t++){
    const float* c_in = (t&1) ? c1 : c0;
    float* c_out      = (t&1) ? c0 : c1;
    k_gates<<<dim3(8,16),256,0,stream>>>(ctxb, hbuf, Wg, part);
    k_lstm_energy<<<256,256,0,stream>>>(part, Gemb, c_in, c_out, hbuf, hall,
                                        mem, emask, out, t);
    k_ctx<<<128,256,0,stream>>>(out, mem, ctxb, ctxa, cov, t);
  }

  k_logitin<<<dim3(8,16),256,0,stream>>>(hall, ctxa, W_cat, b_cat, lib);
  k_logits<<<dim3(8,250),256,0,stream>>>(lib, wlb, b_log, out);
  k_oov<<<200,256,0,stream>>>(out);
  k_scatter<<<1024,128,0,stream>>>(ext, out);
}

// Round 6
// 1550.321 us; speedup vs baseline: 9.8828x; 1.0115x over previous
//
#include <hip/hip_runtime.h>
#include <hip/hip_bf16.h>

#define INF_F 1000000000000.0f

typedef __attribute__((ext_vector_type(8))) short bfrag8;
typedef __attribute__((ext_vector_type(4))) float facc4;

__device__ __forceinline__ float sigf(float x){ return 1.0f/(1.0f + expf(-x)); }
__device__ __forceinline__ short f2bf(float f){
  __hip_bfloat16 h = __float2bfloat16(f);
  return *reinterpret_cast<short*>(&h);
}

// out-region offsets (floats)
#define OFF_LOG 0ull
#define OFF_A   32819200ull
#define OFF_C   33228800ull
#define OFF_E   33638400ull

// ---------------- init ----------------
__global__ __launch_bounds__(256) void k_init(const float* __restrict__ init_s,
    float* __restrict__ hbuf, float* __restrict__ c0, float* __restrict__ ctxb,
    float* __restrict__ cov) {
  int i = blockIdx.x*256 + threadIdx.x;
  if (i < 32*512) { float v = init_s[i]; hbuf[i]=v; c0[i]=v; ctxb[i]=0.0f; }
  if (i < 32*400) cov[i] = 0.0f;
}

// ---------------- b_combo = W_ih@b_red + b_ih + b_hh ----------------
__global__ __launch_bounds__(256) void k_bcombo(const float* __restrict__ W_ih,
    const float* __restrict__ b_red, const float* __restrict__ b_ih,
    const float* __restrict__ b_hh, float* __restrict__ bcomb) {
  int j = blockIdx.x*256 + threadIdx.x;
  if (j >= 2048) return;
  float acc = b_ih[j] + b_hh[j];
  for (int m=0;m<300;m++) acc += W_ih[j*300+m]*b_red[m];
  bcomb[j] = acc;
}

// ---------------- Wct[2048][812] = W_ih[2048x300] @ W_red[300x812] ----------------
__global__ __launch_bounds__(256) void k_wcombo(const float* __restrict__ W_ih,
    const float* __restrict__ W_red, float* __restrict__ Wct) {
  __shared__ float As[16][68];
  __shared__ float Bs[16][68];
  int tid = threadIdx.x;
  int m0 = blockIdx.y*64, n0 = blockIdx.x*64;
  int rl = tid>>2, kq = (tid&3)*4;
  int kl = tid>>4, c4 = (tid&15)*4;
  int tx = tid&15, ty = tid>>4;
  float acc[4][4]={};
  for (int kk=0;kk<300;kk+=16){
    #pragma unroll
    for (int q=0;q<4;q++){
      int kg = kk+kq+q;
      As[kq+q][rl] = (kg<300) ? W_ih[(size_t)(m0+rl)*300 + kg] : 0.0f;
    }
    #pragma unroll
    for (int q=0;q<4;q++){
      int c = n0 + c4 + q;
      Bs[kl][c4+q] = (kk+kl<300 && c<812) ? W_red[(size_t)(kk+kl)*812 + c] : 0.0f;
    }
    __syncthreads();
    #pragma unroll
    for (int k=0;k<16;k++){
      const float* ap=&As[k][ty*4]; const float* bp=&Bs[k][tx*4];
      #pragma unroll
      for (int i=0;i<4;i++)
        #pragma unroll
        for (int j=0;j<4;j++) acc[i][j] += ap[i]*bp[j];
    }
    __syncthreads();
  }
  #pragma unroll
  for (int i=0;i<4;i++)
    #pragma unroll
    for (int j=0;j<4;j++){
      int row = m0+ty*4+i, col = n0+tx*4+j;
      if (col<812) Wct[(size_t)row*812 + col] = acc[i][j];
    }
}

// ---------------- G_emb[1024][2048] = emb[1024x300] @ Wct[:,0:300]^T + b_combo --------
__global__ __launch_bounds__(256) void k_gemb(const float* __restrict__ trg,
    const float* __restrict__ Wct, const float* __restrict__ bcomb,
    float* __restrict__ Gemb) {
  __shared__ float As[16][68];
  __shared__ float Bs[16][68];
  int tid = threadIdx.x;
  int m0 = blockIdx.y*64, n0 = blockIdx.x*64;
  int rl = tid>>2, kq = (tid&3)*4;
  int tx = tid&15, ty = tid>>4;
  float acc[4][4]={};
  int r = m0 + rl;
  const float* arow = trg + (size_t)(r&31)*9600 + (size_t)(r>>5)*300;
  for (int kk=0;kk<300;kk+=16){
    #pragma unroll
    for (int q=0;q<4;q++){
      int kg = kk+kq+q;
      As[kq+q][rl] = (kg<300) ? arow[kg] : 0.0f;
      Bs[kq+q][rl] = (kg<300) ? Wct[(size_t)(n0+rl)*812 + kg] : 0.0f;
    }
    __syncthreads();
    #pragma unroll
    for (int k=0;k<16;k++){
      const float* ap=&As[k][ty*4]; const float* bp=&Bs[k][tx*4];
      #pragma unroll
      for (int i=0;i<4;i++)
        #pragma unroll
        for (int j=0;j<4;j++) acc[i][j] += ap[i]*bp[j];
    }
    __syncthreads();
  }
  #pragma unroll
  for (int i=0;i<4;i++)
    #pragma unroll
    for (int j=0;j<4;j++){
      int rr = m0+ty*4+i, col = n0+tx*4+j;
      Gemb[(size_t)rr*2048 + col] = acc[i][j] + bcomb[col];
    }
}

// ---------------- Wg[1024][2048]: k<512 -> Wct[:,300+k]^T ; k>=512 -> W_hh^T ----------
__global__ __launch_bounds__(256) void k_wgpack(const float* __restrict__ Wct,
    const float* __restrict__ W_hh, float* __restrict__ Wg) {
  int idx = blockIdx.x*256 + threadIdx.x;
  if (idx >= 1024*2048) return;
  int k = idx >> 11, j = idx & 2047;
  Wg[idx] = (k < 512) ? Wct[(size_t)j*812 + 300 + k] : W_hh[(size_t)j*512 + (k-512)];
}

// ---------------- memories = enc @ W_enc^T + b_enc (128x64 tile, 8x4/thread) ---------
// grid dim3(8,100): x = n-block (64 h), y = m-block (128 rows); n-fastest for L3 reuse
__global__ __launch_bounds__(256) void k_memories(const float* __restrict__ A,
    const float* __restrict__ Bw, const float* __restrict__ bias,
    float* __restrict__ mem) {
  __shared__ float As[16][132];
  __shared__ float Bs[16][68];
  int tid = threadIdx.x;
  int n0 = blockIdx.x*64, m0 = blockIdx.y*128;
  int rlA = tid>>1, kqA = (tid&1)*8;
  int rlB = tid>>2, kqB = (tid&3)*4;
  int tx = tid&15, ty = tid>>4;
  float acc[8][4]={};
  for (int kk=0;kk<512;kk+=16){
    float4 a0 = *(const float4*)(A + (size_t)(m0+rlA)*512 + kk+kqA);
    float4 a1 = *(const float4*)(A + (size_t)(m0+rlA)*512 + kk+kqA+4);
    float4 bv = *(const float4*)(Bw + (size_t)(n0+rlB)*512 + kk+kqB);
    As[kqA+0][rlA]=a0.x; As[kqA+1][rlA]=a0.y; As[kqA+2][rlA]=a0.z; As[kqA+3][rlA]=a0.w;
    As[kqA+4][rlA]=a1.x; As[kqA+5][rlA]=a1.y; As[kqA+6][rlA]=a1.z; As[kqA+7][rlA]=a1.w;
    Bs[kqB+0][rlB]=bv.x; Bs[kqB+1][rlB]=bv.y; Bs[kqB+2][rlB]=bv.z; Bs[kqB+3][rlB]=bv.w;
    __syncthreads();
    #pragma unroll
    for (int k=0;k<16;k++){
      float4 b4 = *(const float4*)&Bs[k][tx*4];
      float4 x0 = *(const float4*)&As[k][ty*8];
      float4 x1 = *(const float4*)&As[k][ty*8+4];
      acc[0][0]+=x0.x*b4.x; acc[0][1]+=x0.x*b4.y; acc[0][2]+=x0.x*b4.z; acc[0][3]+=x0.x*b4.w;
      acc[1][0]+=x0.y*b4.x; acc[1][1]+=x0.y*b4.y; acc[1][2]+=x0.y*b4.z; acc[1][3]+=x0.y*b4.w;
      acc[2][0]+=x0.z*b4.x; acc[2][1]+=x0.z*b4.y; acc[2][2]+=x0.z*b4.z; acc[2][3]+=x0.z*b4.w;
      acc[3][0]+=x0.w*b4.x; acc[3][1]+=x0.w*b4.y; acc[3][2]+=x0.w*b4.z; acc[3][3]+=x0.w*b4.w;
      acc[4][0]+=x1.x*b4.x; acc[4][1]+=x1.x*b4.y; acc[4][2]+=x1.x*b4.z; acc[4][3]+=x1.x*b4.w;
      acc[5][0]+=x1.y*b4.x; acc[5][1]+=x1.y*b4.y; acc[5][2]+=x1.y*b4.z; acc[5][3]+=x1.y*b4.w;
      acc[6][0]+=x1.z*b4.x; acc[6][1]+=x1.z*b4.y; acc[6][2]+=x1.z*b4.z; acc[6][3]+=x1.z*b4.w;
      acc[7][0]+=x1.w*b4.x; acc[7][1]+=x1.w*b4.y; acc[7][2]+=x1.w*b4.z; acc[7][3]+=x1.w*b4.w;
    }
    __syncthreads();
  }
  float4 bb = *(const float4*)(bias + n0 + tx*4);
  #pragma unroll
  for (int i=0;i<8;i++){
    int n = m0 + ty*8 + i;
    float4 o;
    o.x = acc[i][0]+bb.x; o.y = acc[i][1]+bb.y;
    o.z = acc[i][2]+bb.z; o.w = acc[i][3]+bb.w;
    *(float4*)(mem + (size_t)n*512 + n0 + tx*4) = o;
  }
}

// ---------------- W_log -> bf16 ----------------
__global__ __launch_bounds__(256) void k_wlogconv(const float* __restrict__ W_log,
    __hip_bfloat16* __restrict__ wlb) {
  int i4 = blockIdx.x*256 + threadIdx.x;
  if (i4 >= 32000*512/4) return;
  const float4 v = *(const float4*)(W_log + (size_t)i4*4);
  size_t o = (size_t)i4*4;
  wlb[o+0] = __float2bfloat16(v.x); wlb[o+1] = __float2bfloat16(v.y);
  wlb[o+2] = __float2bfloat16(v.z); wlb[o+3] = __float2bfloat16(v.w);
}

// ---------------- per-step: gates partial GEMM ----------------
// grid (ks=8, rc=16); partial[ks*32+b][row] = sum_{k in ks chunk} yh[b][k]*Wg[k][row]
__global__ __launch_bounds__(256) void k_gates(const float* __restrict__ ctxb,
    const float* __restrict__ hbuf, const float* __restrict__ Wg,
    float* __restrict__ partials) {
  __shared__ float yh_s[128][32];
  int ks = blockIdx.x;
  int rc = blockIdx.y;
  int tid = threadIdx.x;
  const float* side = (ks < 4) ? ctxb : hbuf;
  int kbase = (ks & 3) * 128;
  {
    int b_l = tid >> 3, kq0 = (tid & 7) * 16;
    const float* src = side + (size_t)b_l*512 + kbase + kq0;
    #pragma unroll
    for (int q=0;q<16;q+=4){
      float4 v = *(const float4*)(src + q);
      yh_s[kq0+q+0][b_l]=v.x; yh_s[kq0+q+1][b_l]=v.y;
      yh_s[kq0+q+2][b_l]=v.z; yh_s[kq0+q+3][b_l]=v.w;
    }
  }
  __syncthreads();
  int tr = tid & 31, bg = tid >> 5;
  int row0 = rc*128 + tr*4;
  float acc[4][4] = {};
  const float* wp = Wg + (size_t)(ks*128)*2048 + row0;
  #pragma unroll 8
  for (int k=0;k<128;k++){
    float4 w = *(const float4*)(wp + (size_t)k*2048);
    float4 y = *(const float4*)&yh_s[k][bg*4];
    acc[0][0]+=w.x*y.x; acc[0][1]+=w.x*y.y; acc[0][2]+=w.x*y.z; acc[0][3]+=w.x*y.w;
    acc[1][0]+=w.y*y.x; acc[1][1]+=w.y*y.y; acc[1][2]+=w.y*y.z; acc[1][3]+=w.y*y.w;
    acc[2][0]+=w.z*y.x; acc[2][1]+=w.z*y.y; acc[2][2]+=w.z*y.z; acc[2][3]+=w.z*y.w;
    acc[3][0]+=w.w*y.x; acc[3][1]+=w.w*y.y; acc[3][2]+=w.w*y.z; acc[3][3]+=w.w*y.w;
  }
  #pragma unroll
  for (int j=0;j<4;j++){
    float4 o; o.x=acc[0][j]; o.y=acc[1][j]; o.z=acc[2][j]; o.w=acc[3][j];
    *(float4*)(partials + (size_t)(ks*32 + bg*4 + j)*2048 + row0) = o;
  }
}

// ---------------- per-step: partial reduce + LSTM (redundant) + energy chunk --------
// grid 256 linear blocks: b = blk&31, sc = blk>>5
__global__ __launch_bounds__(256) void k_lstm_energy(const float* __restrict__ part,
    const float* __restrict__ Gemb,
    const float* __restrict__ c_in, float* __restrict__ c_out,
    float* __restrict__ hbuf, float* __restrict__ hall,
    const float* __restrict__ mem, const int* __restrict__ emask,
    float* __restrict__ out, int t) {
  __shared__ float hl[512];
  int blk = blockIdx.x, tid = threadIdx.x;
  int b = blk & 31, sc = blk >> 5;
  int r = t*32 + b;
  int lane = tid & 63, w = tid >> 6;
  const float* gp = Gemb + (size_t)r*2048;
  #pragma unroll
  for (int jj=0; jj<2; jj++){
    int j = tid + jj*256;
    float g[4];
    #pragma unroll
    for (int gi=0; gi<4; gi++){
      int row = gi*512 + j;
      float v = gp[row];
      #pragma unroll
      for (int ks=0; ks<8; ks++)
        v += part[(size_t)(ks*32+b)*2048 + row];
      g[gi] = v;
    }
    float cp = c_in[b*512+j];
    float cn = sigf(g[1])*cp + sigf(g[0])*tanhf(g[2]);
    float hn = sigf(g[3])*tanhf(cn);
    hl[j] = hn;
    if (sc==0){
      c_out[b*512+j]=cn; hbuf[b*512+j]=hn; hall[(size_t)r*512+j]=hn;
    }
  }
  __syncthreads();
  float4 h0 = *(const float4*)&hl[lane*8];
  float4 h1 = *(const float4*)&hl[lane*8+4];
  const float* mb = mem + (size_t)b*204800;
  const int* em = emask + b*400;
  for (int i=0;i<13;i++){
    int s_l = i*4 + w;
    if (s_l < 50){
      int s = sc*50 + s_l;
      const float4* mp = (const float4*)(mb + (size_t)s*512 + lane*8);
      float4 m0 = mp[0], m1 = mp[1];
      float acc = h0.x*m0.x + h0.y*m0.y + h0.z*m0.z + h0.w*m0.w
                + h1.x*m1.x + h1.y*m1.y + h1.z*m1.z + h1.w*m1.w;
      #pragma unroll
      for (int off=32; off; off>>=1) acc += __shfl_xor(acc, off);
      if (lane==0){
        out[OFF_E + (size_t)r*400 + s] = (em[s]==0) ? -INF_F : acc;
      }
    }
  }
}

// ---------------- per-step: softmax (redundant) + ctx chunk + attn/cov -------------
// grid 128 linear blocks: b = blk&31, hc = blk>>5 (4 chunks x 128 h)
__global__ __launch_bounds__(256) void k_ctx(float* __restrict__ out,
    const float* __restrict__ mem, float* __restrict__ ctxb, float* __restrict__ ctxa,
    float* __restrict__ cov, int t) {
  __shared__ float ps[400];
  __shared__ float red[8];
  __shared__ float tmp[128];
  int blk = blockIdx.x, tid = threadIdx.x;
  int b = blk & 31, hc = blk >> 5;
  int r = t*32 + b;
  int lane = tid & 63, w = tid >> 6;
  float e0 = out[OFF_E + (size_t)r*400 + tid];
  float e1 = (tid < 144) ? out[OFF_E + (size_t)r*400 + tid + 256] : -3.4e38f;
  float lm = fmaxf(e0, e1);
  #pragma unroll
  for (int off=32; off; off>>=1) lm = fmaxf(lm, __shfl_xor(lm, off));
  if (lane==0) red[w] = lm;
  __syncthreads();
  float m = fmaxf(fmaxf(red[0],red[1]), fmaxf(red[2],red[3]));
  float pv0 = expf(e0 - m);
  float pv1 = (tid < 144) ? expf(e1 - m) : 0.0f;
  float sv = pv0 + pv1;
  #pragma unroll
  for (int off=32; off; off>>=1) sv += __shfl_xor(sv, off);
  if (lane==0) red[4+w] = sv;
  __syncthreads();
  float inv = 1.0f/(red[4]+red[5]+red[6]+red[7]);
  ps[tid] = pv0*inv;
  if (tid < 144) ps[tid+256] = pv1*inv;
  __syncthreads();
  // ctx chunk: 128 h, two s-halves
  int hloc = tid & 127, sh = tid >> 7;
  int h = hc*128 + hloc;
  const float* mq = mem + (size_t)b*204800 + h;
  float acc = 0.0f;
  {
    const float* mqs = mq + (size_t)sh*200*512;
    const float* pss = &ps[sh*200];
    #pragma unroll 8
    for (int s=0;s<200;s++) acc += pss[s]*mqs[(size_t)s*512];
  }
  if (sh==1) tmp[hloc] = acc;
  __syncthreads();
  if (sh==0){
    float v = acc + tmp[hloc];
    ctxb[b*512+h] = v;
    ctxa[(size_t)r*512+h] = v;
  }
  if (hc==0){
    for (int s=tid; s<400; s+=256){
      float a = ps[s];
      out[OFF_A + (size_t)r*400 + s] = a;
      float cv = cov[b*400+s];
      out[OFF_C + (size_t)r*400 + s] = cv;
      cov[b*400+s] = cv + a;
    }
  }
}

// swizzled LDS byte offset: row in [0,128), slot in [0,4) (16B granules of a 64B row)
__device__ __forceinline__ int lds_off(int row, int slot) {
  return (row<<6) + (((slot ^ ((row>>1)&3))&3)<<4);
}

// ---------------- logit_in = tanh([h_all|ctx_all]@W_cat^T + b_cat) -> bf16 (MFMA) ----
// grid dim3(8,4): m0 = x*128 (1024 rows), n0 = y*128 (512 cols); K=1024 in 32 steps
__global__ __launch_bounds__(256) void k_logitin(const float* __restrict__ hall,
    const float* __restrict__ ctxa, const float* __restrict__ W_cat,
    const float* __restrict__ b_cat, __hip_bfloat16* __restrict__ lib) {
  __shared__ short As[4096];
  __shared__ short Bs[4096];
  int tid = threadIdx.x;
  int m0 = blockIdx.x*128, n0 = blockIdx.y*128;
  int w = tid>>6, lane = tid&63;
  int wr = w>>1, wc = w&1;
  int lr = lane&15, kg2 = lane>>4;

  int srow = tid>>1;
  int half = tid&1;
  int wo0 = lds_off(srow, half*2), wo1 = lds_off(srow, half*2+1);

  int raoff[4], rboff[4];
  #pragma unroll
  for (int q=0;q<4;q++){
    raoff[q] = lds_off(wr*64 + q*16 + lr, kg2);
    rboff[q] = lds_off(wc*64 + q*16 + lr, kg2);
  }

  facc4 acc[4][4] = {};
  for (int ks=0; ks<32; ks++){
    int k0 = ks*32 + half*16;
    const float* arow = (k0 < 512) ? (hall + (size_t)(m0+srow)*512 + k0)
                                   : (ctxa + (size_t)(m0+srow)*512 + k0 - 512);
    const float* brow = W_cat + (size_t)(n0+srow)*1024 + k0;
    short a16[16], b16[16];
    #pragma unroll
    for (int q=0;q<16;q+=4){
      float4 av = *(const float4*)(arow+q);
      float4 bv = *(const float4*)(brow+q);
      a16[q+0]=f2bf(av.x); a16[q+1]=f2bf(av.y); a16[q+2]=f2bf(av.z); a16[q+3]=f2bf(av.w);
      b16[q+0]=f2bf(bv.x); b16[q+1]=f2bf(bv.y); b16[q+2]=f2bf(bv.z); b16[q+3]=f2bf(bv.w);
    }
    __syncthreads();
    *(bfrag8*)((char*)As + wo0) = *(const bfrag8*)&a16[0];
    *(bfrag8*)((char*)As + wo1) = *(const bfrag8*)&a16[8];
    *(bfrag8*)((char*)Bs + wo0) = *(const bfrag8*)&b16[0];
    *(bfrag8*)((char*)Bs + wo1) = *(const bfrag8*)&b16[8];
    __syncthreads();
    bfrag8 af[4], bf[4];
    #pragma unroll
    for (int q=0;q<4;q++){
      af[q] = *(const bfrag8*)((char*)As + raoff[q]);
      bf[q] = *(const bfrag8*)((char*)Bs + rboff[q]);
    }
    #pragma unroll
    for (int mi=0;mi<4;mi++)
      #pragma unroll
      for (int ni=0;ni<4;ni++)
        acc[mi][ni] = __builtin_amdgcn_mfma_f32_16x16x32_bf16(af[mi], bf[ni], acc[mi][ni], 0,0,0);
  }

  #pragma unroll
  for (int mi=0;mi<4;mi++){
    int row = m0 + wr*64 + mi*16 + kg2*4;
    #pragma unroll
    for (int ni=0;ni<4;ni++){
      int col = n0 + wc*64 + ni*16 + lr;
      float bc = b_cat[col];
      #pragma unroll
      for (int q=0;q<4;q++){
        float v = tanhf(acc[mi][ni][q] + bc);
        lib[(size_t)(row+q)*512 + col] = __float2bfloat16(v);
      }
    }
  }
}

// ---------------- logits = logit_in @ W_log^T + b_log (bf16 MFMA, 128x128 tile) -------
__global__ __launch_bounds__(256) void k_logits(const __hip_bfloat16* __restrict__ Ab,
    const __hip_bfloat16* __restrict__ Wb, const float* __restrict__ b_log,
    float* __restrict__ out) {
  __shared__ short As[4096];
  __shared__ short Bs[4096];
  int tid = threadIdx.x;
  int m0 = blockIdx.x*128, n0 = blockIdx.y*128;
  int w = tid>>6, lane = tid&63;
  int wr = w>>1, wc = w&1;
  int lr = lane&15, kg2 = lane>>4;
  const short* A = (const short*)Ab;
  const short* W = (const short*)Wb;

  int srow = tid>>1;
  int ss   = (tid&1)*2;
  const short* ga = A + (size_t)(m0+srow)*512 + ss*8;
  const short* gw = W + (size_t)(n0+srow)*512 + ss*8;
  int wo0 = lds_off(srow, ss), wo1 = lds_off(srow, ss+1);

  int raoff[4], rboff[4];
  #pragma unroll
  for (int q=0;q<4;q++){
    raoff[q] = lds_off(wr*64 + q*16 + lr, kg2);
    rboff[q] = lds_off(wc*64 + q*16 + lr, kg2);
  }

  facc4 acc[4][4] = {};
  bfrag8 ra0 = *(const bfrag8*)(ga);
  bfrag8 ra1 = *(const bfrag8*)(ga+8);
  bfrag8 rb0 = *(const bfrag8*)(gw);
  bfrag8 rb1 = *(const bfrag8*)(gw+8);

  for (int i=0;i<16;i++){
    __syncthreads();
    *(bfrag8*)((char*)As + wo0) = ra0;
    *(bfrag8*)((char*)As + wo1) = ra1;
    *(bfrag8*)((char*)Bs + wo0) = rb0;
    *(bfrag8*)((char*)Bs + wo1) = rb1;
    __syncthreads();
    if (i<15){
      ga += 32; gw += 32;
      ra0 = *(const bfrag8*)(ga);
      ra1 = *(const bfrag8*)(ga+8);
      rb0 = *(const bfrag8*)(gw);
      rb1 = *(const bfrag8*)(gw+8);
    }
    bfrag8 af[4], bf[4];
    #pragma unroll
    for (int q=0;q<4;q++){
      af[q] = *(const bfrag8*)((char*)As + raoff[q]);
      bf[q] = *(const bfrag8*)((char*)Bs + rboff[q]);
    }
    #pragma unroll
    for (int mi=0;mi<4;mi++)
      #pragma unroll
      for (int ni=0;ni<4;ni++)
        acc[mi][ni] = __builtin_amdgcn_mfma_f32_16x16x32_bf16(af[mi], bf[ni], acc[mi][ni], 0,0,0);
  }

  #pragma unroll
  for (int mi=0;mi<4;mi++){
    int row = m0 + wr*64 + mi*16 + kg2*4;
    #pragma unroll
    for (int ni=0;ni<4;ni++){
      int col = n0 + wc*64 + ni*16 + lr;
      float bl = b_log[col];
      #pragma unroll
      for (int q=0;q<4;q++){
        float v = acc[mi][ni][q] + bl;
        out[(size_t)(row+q)*32050 + col] = (v == 0.0f) ? -INF_F : v;
      }
    }
  }
}

// ---------------- scatter-max of energies into extended logits (+ OOV fill) ---------
__global__ __launch_bounds__(128) void k_scatter(const int* __restrict__ ext_src,
    float* __restrict__ out) {
  __shared__ int tok[400];
  __shared__ float ev[400];
  int rr = blockIdx.x;
  int b = rr & 31;
  int tid = threadIdx.x;
  if (tid < 50) out[(size_t)rr*32050 + 32000 + tid] = -INF_F;
  for (int s=tid; s<400; s+=128){
    tok[s] = ext_src[b*400+s];
    ev[s]  = out[OFF_E + (size_t)rr*400 + s];
  }
  __syncthreads();
  for (int s=tid; s<400; s+=128){
    int tk = tok[s];
    float m = ev[s];
    bool first = true;
    for (int s2=0; s2<400; s2++){
      if (tok[s2]==tk){
        if (s2 < s) first=false;
        m = fmaxf(m, ev[s2]);
      }
    }
    if (first && m != -INF_F){
      size_t idx = (size_t)rr*32050 + tk;
      float wv = out[idx];
      float extv = (wv == -INF_F) ? 0.0f : wv;
      float nv = extv + m;
      out[idx] = (nv == 0.0f) ? -INF_F : nv;
    }
  }
}

extern "C" void kernel_launch(void* const* d_in, const int* in_sizes, int n_in,
                              void* d_out, int out_size, void* d_ws, size_t ws_size,
                              hipStream_t stream) {
  const float* trg   = (const float*)d_in[0];
  const int*   ext   = (const int*)  d_in[1];
  const float* inits = (const float*)d_in[2];
  const float* enc   = (const float*)d_in[3];
  const int*   emask = (const int*)  d_in[4];
  const float* W_enc = (const float*)d_in[5];
  const float* b_enc = (const float*)d_in[6];
  const float* W_red = (const float*)d_in[7];
  const float* b_red = (const float*)d_in[8];
  const float* W_ih  = (const float*)d_in[9];
  const float* W_hh  = (const float*)d_in[10];
  const float* b_ih  = (const float*)d_in[11];
  const float* b_hh  = (const float*)d_in[12];
  const float* W_cat = (const float*)d_in[13];
  const float* b_cat = (const float*)d_in[14];
  const float* W_log = (const float*)d_in[15];
  const float* b_log = (const float*)d_in[16];
  float* out = (float*)d_out;
  float* ws  = (float*)d_ws;

  float* mem   = ws + 0ull;          // 6,553,600
  float* Wg    = ws + 6553600ull;    // 2,097,152
  float* Wct   = ws + 8650752ull;    // 1,662,976
  float* Gemb  = ws + 10313728ull;   // 2,097,152
  float* bcomb = ws + 12410880ull;   // 2,048
  float* hbuf  = ws + 12412928ull;   // 16,384
  float* c0    = ws + 12429312ull;   // 16,384
  float* c1    = ws + 12445696ull;   // 16,384
  float* ctxb  = ws + 12462080ull;   // 16,384
  float* hall  = ws + 12478464ull;   // 524,288
  float* ctxa  = ws + 13002752ull;   // 524,288
  float* cov   = ws + 13527040ull;   // 12,800
  float* part  = ws + 13539840ull;   // 524,288
  __hip_bfloat16* lib = (__hip_bfloat16*)(ws + 14590464ull);   // 262,144 floats
  __hip_bfloat16* wlb = (__hip_bfloat16*)(ws + 14852608ull);   // 8,192,000 floats

  k_init<<<64,256,0,stream>>>(inits, hbuf, c0, ctxb, cov);
  k_bcombo<<<8,256,0,stream>>>(W_ih, b_red, b_ih, b_hh, bcomb);
  k_wcombo<<<dim3(13,32),256,0,stream>>>(W_ih, W_red, Wct);
  k_gemb<<<dim3(32,16),256,0,stream>>>(trg, Wct, bcomb, Gemb);
  k_wgpack<<<8192,256,0,stream>>>(Wct, W_hh, Wg);
  k_memories<<<dim3(8,100),256,0,stream>>>(enc, W_enc, b_enc, mem);
  k_wlogconv<<<16000,256,0,stream>>>(W_log, wlb);

  for (int t=0;t<32;t++){
    const float* c_in = (t&1) ? c1 : c0;
    float* c_out      = (t&1) ? c0 : c1;
    k_gates<<<dim3(8,16),256,0,stream>>>(ctxb, hbuf, Wg, part);
    k_lstm_energy<<<256,256,0,stream>>>(part, Gemb, c_in, c_out, hbuf, hall,
                                        mem, emask, out, t);
    k_ctx<<<128,256,0,stream>>>(out, mem, ctxb, ctxa, cov, t);
  }

  k_logitin<<<dim3(8,4),256,0,stream>>>(hall, ctxa, W_cat, b_cat, lib);
  k_logits<<<dim3(8,250),256,0,stream>>>(lib, wlb, b_log, out);
  k_scatter<<<1024,128,0,stream>>>(ext, out);
}

// Round 7
// 1492.161 us; speedup vs baseline: 10.2680x; 1.0390x over previous
//
#include <hip/hip_runtime.h>
#include <hip/hip_bf16.h>

#define INF_F 1000000000000.0f

typedef __attribute__((ext_vector_type(8))) short bfrag8;
typedef __attribute__((ext_vector_type(4))) float facc4;
typedef __attribute__((ext_vector_type(4))) short short4v;

__device__ __forceinline__ float sigf(float x){ return 1.0f/(1.0f + expf(-x)); }
__device__ __forceinline__ short f2bf(float f){
  __hip_bfloat16 h = __float2bfloat16(f);
  return *reinterpret_cast<short*>(&h);
}
__device__ __forceinline__ float bf2f(short s){
  unsigned u = ((unsigned)(unsigned short)s) << 16;
  return *reinterpret_cast<float*>(&u);
}

// out-region offsets (floats)
#define OFF_LOG 0ull
#define OFF_A   32819200ull
#define OFF_C   33228800ull
#define OFF_E   33638400ull

// ---------------- init ----------------
__global__ __launch_bounds__(256) void k_init(const float* __restrict__ init_s,
    float* __restrict__ hbuf, float* __restrict__ c0, float* __restrict__ ctxb,
    float* __restrict__ cov) {
  int i = blockIdx.x*256 + threadIdx.x;
  if (i < 32*512) { float v = init_s[i]; hbuf[i]=v; c0[i]=v; ctxb[i]=0.0f; }
  if (i < 32*400) cov[i] = 0.0f;
}

// ---------------- b_combo = W_ih@b_red + b_ih + b_hh ----------------
__global__ __launch_bounds__(256) void k_bcombo(const float* __restrict__ W_ih,
    const float* __restrict__ b_red, const float* __restrict__ b_ih,
    const float* __restrict__ b_hh, float* __restrict__ bcomb) {
  int j = blockIdx.x*256 + threadIdx.x;
  if (j >= 2048) return;
  float acc = b_ih[j] + b_hh[j];
  for (int m=0;m<300;m++) acc += W_ih[j*300+m]*b_red[m];
  bcomb[j] = acc;
}

// ---------------- Wct[2048][812] = W_ih[2048x300] @ W_red[300x812] ----------------
__global__ __launch_bounds__(256) void k_wcombo(const float* __restrict__ W_ih,
    const float* __restrict__ W_red, float* __restrict__ Wct) {
  __shared__ float As[16][68];
  __shared__ float Bs[16][68];
  int tid = threadIdx.x;
  int m0 = blockIdx.y*64, n0 = blockIdx.x*64;
  int rl = tid>>2, kq = (tid&3)*4;
  int kl = tid>>4, c4 = (tid&15)*4;
  int tx = tid&15, ty = tid>>4;
  float acc[4][4]={};
  for (int kk=0;kk<300;kk+=16){
    #pragma unroll
    for (int q=0;q<4;q++){
      int kg = kk+kq+q;
      As[kq+q][rl] = (kg<300) ? W_ih[(size_t)(m0+rl)*300 + kg] : 0.0f;
    }
    #pragma unroll
    for (int q=0;q<4;q++){
      int c = n0 + c4 + q;
      Bs[kl][c4+q] = (kk+kl<300 && c<812) ? W_red[(size_t)(kk+kl)*812 + c] : 0.0f;
    }
    __syncthreads();
    #pragma unroll
    for (int k=0;k<16;k++){
      const float* ap=&As[k][ty*4]; const float* bp=&Bs[k][tx*4];
      #pragma unroll
      for (int i=0;i<4;i++)
        #pragma unroll
        for (int j=0;j<4;j++) acc[i][j] += ap[i]*bp[j];
    }
    __syncthreads();
  }
  #pragma unroll
  for (int i=0;i<4;i++)
    #pragma unroll
    for (int j=0;j<4;j++){
      int row = m0+ty*4+i, col = n0+tx*4+j;
      if (col<812) Wct[(size_t)row*812 + col] = acc[i][j];
    }
}

// ---------------- G_emb[1024][2048] = emb[1024x300] @ Wct[:,0:300]^T + b_combo --------
__global__ __launch_bounds__(256) void k_gemb(const float* __restrict__ trg,
    const float* __restrict__ Wct, const float* __restrict__ bcomb,
    float* __restrict__ Gemb) {
  __shared__ float As[16][68];
  __shared__ float Bs[16][68];
  int tid = threadIdx.x;
  int m0 = blockIdx.y*64, n0 = blockIdx.x*64;
  int rl = tid>>2, kq = (tid&3)*4;
  int tx = tid&15, ty = tid>>4;
  float acc[4][4]={};
  int r = m0 + rl;
  const float* arow = trg + (size_t)(r&31)*9600 + (size_t)(r>>5)*300;
  for (int kk=0;kk<300;kk+=16){
    #pragma unroll
    for (int q=0;q<4;q++){
      int kg = kk+kq+q;
      As[kq+q][rl] = (kg<300) ? arow[kg] : 0.0f;
      Bs[kq+q][rl] = (kg<300) ? Wct[(size_t)(n0+rl)*812 + kg] : 0.0f;
    }
    __syncthreads();
    #pragma unroll
    for (int k=0;k<16;k++){
      const float* ap=&As[k][ty*4]; const float* bp=&Bs[k][tx*4];
      #pragma unroll
      for (int i=0;i<4;i++)
        #pragma unroll
        for (int j=0;j<4;j++) acc[i][j] += ap[i]*bp[j];
    }
    __syncthreads();
  }
  #pragma unroll
  for (int i=0;i<4;i++)
    #pragma unroll
    for (int j=0;j<4;j++){
      int rr = m0+ty*4+i, col = n0+tx*4+j;
      Gemb[(size_t)rr*2048 + col] = acc[i][j] + bcomb[col];
    }
}

// ---------------- Wg[1024][2048]: k<512 -> Wct[:,300+k]^T ; k>=512 -> W_hh^T ----------
__global__ __launch_bounds__(256) void k_wgpack(const float* __restrict__ Wct,
    const float* __restrict__ W_hh, float* __restrict__ Wg) {
  int idx = blockIdx.x*256 + threadIdx.x;
  if (idx >= 1024*2048) return;
  int k = idx >> 11, j = idx & 2047;
  Wg[idx] = (k < 512) ? Wct[(size_t)j*812 + 300 + k] : W_hh[(size_t)j*512 + (k-512)];
}

// ---------------- split enc & W_enc into bf16 hi/lo pairs ----------------
// grid 6656 blocks: first 1,638,400 i4-units = enc (6,553,600 f), rest = W_enc (262,144 f)
__global__ __launch_bounds__(256) void k_convsplit(const float* __restrict__ enc,
    const float* __restrict__ W_enc, short* __restrict__ ehi, short* __restrict__ elo,
    short* __restrict__ whi, short* __restrict__ wlo) {
  int i4 = blockIdx.x*256 + threadIdx.x;
  const float* src; short* dhi; short* dlo; size_t off;
  if (i4 < 1638400) { src = enc;   dhi = ehi; dlo = elo; off = (size_t)i4*4; }
  else { int j4 = i4 - 1638400; if (j4 >= 65536) return;
         src = W_enc; dhi = whi; dlo = wlo; off = (size_t)j4*4; }
  float4 v = *(const float4*)(src + off);
  float f[4] = {v.x, v.y, v.z, v.w};
  short4v h, l;
  #pragma unroll
  for (int q=0;q<4;q++){
    short hb = f2bf(f[q]);
    float r = f[q] - bf2f(hb);
    h[q] = hb; l[q] = f2bf(r);
  }
  *(short4v*)(dhi + off) = h;
  *(short4v*)(dlo + off) = l;
}

// swizzled LDS byte offset: row in [0,128), slot in [0,4) (16B granules of a 64B row)
__device__ __forceinline__ int lds_off(int row, int slot) {
  return (row<<6) + (((slot ^ ((row>>1)&3))&3)<<4);
}

// ---------------- memories = enc @ W_enc^T + b_enc  (split-precision 3xbf16 MFMA) ----
// grid dim3(100,4): m0 = x*128 (12800 rows), n0 = y*128 (512 cols); K=512
__global__ __launch_bounds__(256) void k_memories(const short* __restrict__ Ahg,
    const short* __restrict__ Alg, const short* __restrict__ Bhg,
    const short* __restrict__ Blg, const float* __restrict__ bias,
    float* __restrict__ mem) {
  __shared__ short Ah[4096];
  __shared__ short Al[4096];
  __shared__ short Bh[4096];
  __shared__ short Bl[4096];
  int tid = threadIdx.x;
  int m0 = blockIdx.x*128, n0 = blockIdx.y*128;
  int w = tid>>6, lane = tid&63;
  int wr = w>>1, wc = w&1;
  int lr = lane&15, kg2 = lane>>4;

  int srow = tid>>1;
  int ss   = (tid&1)*2;
  const short* gah = Ahg + (size_t)(m0+srow)*512 + ss*8;
  const short* gal = Alg + (size_t)(m0+srow)*512 + ss*8;
  const short* gbh = Bhg + (size_t)(n0+srow)*512 + ss*8;
  const short* gbl = Blg + (size_t)(n0+srow)*512 + ss*8;
  int wo0 = lds_off(srow, ss), wo1 = lds_off(srow, ss+1);

  int raoff[4], rboff[4];
  #pragma unroll
  for (int q=0;q<4;q++){
    raoff[q] = lds_off(wr*64 + q*16 + lr, kg2);
    rboff[q] = lds_off(wc*64 + q*16 + lr, kg2);
  }

  facc4 acc[4][4] = {};
  bfrag8 rah0 = *(const bfrag8*)(gah);
  bfrag8 rah1 = *(const bfrag8*)(gah+8);
  bfrag8 ral0 = *(const bfrag8*)(gal);
  bfrag8 ral1 = *(const bfrag8*)(gal+8);
  bfrag8 rbh0 = *(const bfrag8*)(gbh);
  bfrag8 rbh1 = *(const bfrag8*)(gbh+8);
  bfrag8 rbl0 = *(const bfrag8*)(gbl);
  bfrag8 rbl1 = *(const bfrag8*)(gbl+8);

  for (int i=0;i<16;i++){
    __syncthreads();
    *(bfrag8*)((char*)Ah + wo0) = rah0;
    *(bfrag8*)((char*)Ah + wo1) = rah1;
    *(bfrag8*)((char*)Al + wo0) = ral0;
    *(bfrag8*)((char*)Al + wo1) = ral1;
    *(bfrag8*)((char*)Bh + wo0) = rbh0;
    *(bfrag8*)((char*)Bh + wo1) = rbh1;
    *(bfrag8*)((char*)Bl + wo0) = rbl0;
    *(bfrag8*)((char*)Bl + wo1) = rbl1;
    __syncthreads();
    if (i<15){
      gah += 32; gal += 32; gbh += 32; gbl += 32;
      rah0 = *(const bfrag8*)(gah);
      rah1 = *(const bfrag8*)(gah+8);
      ral0 = *(const bfrag8*)(gal);
      ral1 = *(const bfrag8*)(gal+8);
      rbh0 = *(const bfrag8*)(gbh);
      rbh1 = *(const bfrag8*)(gbh+8);
      rbl0 = *(const bfrag8*)(gbl);
      rbl1 = *(const bfrag8*)(gbl+8);
    }
    bfrag8 afh[4], afl[4], bfh[4], bfl[4];
    #pragma unroll
    for (int q=0;q<4;q++){
      afh[q] = *(const bfrag8*)((char*)Ah + raoff[q]);
      afl[q] = *(const bfrag8*)((char*)Al + raoff[q]);
      bfh[q] = *(const bfrag8*)((char*)Bh + rboff[q]);
      bfl[q] = *(const bfrag8*)((char*)Bl + rboff[q]);
    }
    #pragma unroll
    for (int mi=0;mi<4;mi++)
      #pragma unroll
      for (int ni=0;ni<4;ni++){
        acc[mi][ni] = __builtin_amdgcn_mfma_f32_16x16x32_bf16(afl[mi], bfh[ni], acc[mi][ni], 0,0,0);
        acc[mi][ni] = __builtin_amdgcn_mfma_f32_16x16x32_bf16(afh[mi], bfl[ni], acc[mi][ni], 0,0,0);
        acc[mi][ni] = __builtin_amdgcn_mfma_f32_16x16x32_bf16(afh[mi], bfh[ni], acc[mi][ni], 0,0,0);
      }
  }

  #pragma unroll
  for (int mi=0;mi<4;mi++){
    int row = m0 + wr*64 + mi*16 + kg2*4;
    #pragma unroll
    for (int ni=0;ni<4;ni++){
      int col = n0 + wc*64 + ni*16 + lr;
      float bl = bias[col];
      #pragma unroll
      for (int q=0;q<4;q++)
        mem[(size_t)(row+q)*512 + col] = acc[mi][ni][q] + bl;
    }
  }
}

// ---------------- W_log -> bf16 ----------------
__global__ __launch_bounds__(256) void k_wlogconv(const float* __restrict__ W_log,
    __hip_bfloat16* __restrict__ wlb) {
  int i4 = blockIdx.x*256 + threadIdx.x;
  if (i4 >= 32000*512/4) return;
  const float4 v = *(const float4*)(W_log + (size_t)i4*4);
  size_t o = (size_t)i4*4;
  wlb[o+0] = __float2bfloat16(v.x); wlb[o+1] = __float2bfloat16(v.y);
  wlb[o+2] = __float2bfloat16(v.z); wlb[o+3] = __float2bfloat16(v.w);
}

// ---------------- per-step: gates partial GEMM ----------------
// grid (ks=8, rc=16); partial[ks*32+b][row] = sum_{k in ks chunk} yh[b][k]*Wg[k][row]
__global__ __launch_bounds__(256) void k_gates(const float* __restrict__ ctxb,
    const float* __restrict__ hbuf, const float* __restrict__ Wg,
    float* __restrict__ partials) {
  __shared__ float yh_s[128][32];
  int ks = blockIdx.x;
  int rc = blockIdx.y;
  int tid = threadIdx.x;
  const float* side = (ks < 4) ? ctxb : hbuf;
  int kbase = (ks & 3) * 128;
  {
    int b_l = tid >> 3, kq0 = (tid & 7) * 16;
    const float* src = side + (size_t)b_l*512 + kbase + kq0;
    #pragma unroll
    for (int q=0;q<16;q+=4){
      float4 v = *(const float4*)(src + q);
      yh_s[kq0+q+0][b_l]=v.x; yh_s[kq0+q+1][b_l]=v.y;
      yh_s[kq0+q+2][b_l]=v.z; yh_s[kq0+q+3][b_l]=v.w;
    }
  }
  __syncthreads();
  int tr = tid & 31, bg = tid >> 5;
  int row0 = rc*128 + tr*4;
  float acc[4][4] = {};
  const float* wp = Wg + (size_t)(ks*128)*2048 + row0;
  #pragma unroll 8
  for (int k=0;k<128;k++){
    float4 w = *(const float4*)(wp + (size_t)k*2048);
    float4 y = *(const float4*)&yh_s[k][bg*4];
    acc[0][0]+=w.x*y.x; acc[0][1]+=w.x*y.y; acc[0][2]+=w.x*y.z; acc[0][3]+=w.x*y.w;
    acc[1][0]+=w.y*y.x; acc[1][1]+=w.y*y.y; acc[1][2]+=w.y*y.z; acc[1][3]+=w.y*y.w;
    acc[2][0]+=w.z*y.x; acc[2][1]+=w.z*y.y; acc[2][2]+=w.z*y.z; acc[2][3]+=w.z*y.w;
    acc[3][0]+=w.w*y.x; acc[3][1]+=w.w*y.y; acc[3][2]+=w.w*y.z; acc[3][3]+=w.w*y.w;
  }
  #pragma unroll
  for (int j=0;j<4;j++){
    float4 o; o.x=acc[0][j]; o.y=acc[1][j]; o.z=acc[2][j]; o.w=acc[3][j];
    *(float4*)(partials + (size_t)(ks*32 + bg*4 + j)*2048 + row0) = o;
  }
}

// ---------------- per-step: partial reduce + LSTM (redundant) + energy chunk --------
// grid 256 linear blocks: b = blk&31, sc = blk>>5
__global__ __launch_bounds__(256) void k_lstm_energy(const float* __restrict__ part,
    const float* __restrict__ Gemb,
    const float* __restrict__ c_in, float* __restrict__ c_out,
    float* __restrict__ hbuf, float* __restrict__ hall,
    const float* __restrict__ mem, const int* __restrict__ emask,
    float* __restrict__ out, int t) {
  __shared__ float hl[512];
  int blk = blockIdx.x, tid = threadIdx.x;
  int b = blk & 31, sc = blk >> 5;
  int r = t*32 + b;
  int lane = tid & 63, w = tid >> 6;
  const float* gp = Gemb + (size_t)r*2048;
  #pragma unroll
  for (int jj=0; jj<2; jj++){
    int j = tid + jj*256;
    float g[4];
    #pragma unroll
    for (int gi=0; gi<4; gi++){
      int row = gi*512 + j;
      float v = gp[row];
      #pragma unroll
      for (int ks=0; ks<8; ks++)
        v += part[(size_t)(ks*32+b)*2048 + row];
      g[gi] = v;
    }
    float cp = c_in[b*512+j];
    float cn = sigf(g[1])*cp + sigf(g[0])*tanhf(g[2]);
    float hn = sigf(g[3])*tanhf(cn);
    hl[j] = hn;
    if (sc==0){
      c_out[b*512+j]=cn; hbuf[b*512+j]=hn; hall[(size_t)r*512+j]=hn;
    }
  }
  __syncthreads();
  float4 h0 = *(const float4*)&hl[lane*8];
  float4 h1 = *(const float4*)&hl[lane*8+4];
  const float* mb = mem + (size_t)b*204800;
  const int* em = emask + b*400;
  for (int i=0;i<13;i++){
    int s_l = i*4 + w;
    if (s_l < 50){
      int s = sc*50 + s_l;
      const float4* mp = (const float4*)(mb + (size_t)s*512 + lane*8);
      float4 m0 = mp[0], m1 = mp[1];
      float acc = h0.x*m0.x + h0.y*m0.y + h0.z*m0.z + h0.w*m0.w
                + h1.x*m1.x + h1.y*m1.y + h1.z*m1.z + h1.w*m1.w;
      #pragma unroll
      for (int off=32; off; off>>=1) acc += __shfl_xor(acc, off);
      if (lane==0){
        out[OFF_E + (size_t)r*400 + s] = (em[s]==0) ? -INF_F : acc;
      }
    }
  }
}

// ---------------- per-step: softmax (redundant) + ctx chunk + attn/cov -------------
// grid 128 linear blocks: b = blk&31, hc = blk>>5 (4 chunks x 128 h)
__global__ __launch_bounds__(256) void k_ctx(float* __restrict__ out,
    const float* __restrict__ mem, float* __restrict__ ctxb, float* __restrict__ ctxa,
    float* __restrict__ cov, int t) {
  __shared__ float ps[400];
  __shared__ float red[8];
  __shared__ float tmp[128];
  int blk = blockIdx.x, tid = threadIdx.x;
  int b = blk & 31, hc = blk >> 5;
  int r = t*32 + b;
  int lane = tid & 63, w = tid >> 6;
  float e0 = out[OFF_E + (size_t)r*400 + tid];
  float e1 = (tid < 144) ? out[OFF_E + (size_t)r*400 + tid + 256] : -3.4e38f;
  float lm = fmaxf(e0, e1);
  #pragma unroll
  for (int off=32; off; off>>=1) lm = fmaxf(lm, __shfl_xor(lm, off));
  if (lane==0) red[w] = lm;
  __syncthreads();
  float m = fmaxf(fmaxf(red[0],red[1]), fmaxf(red[2],red[3]));
  float pv0 = expf(e0 - m);
  float pv1 = (tid < 144) ? expf(e1 - m) : 0.0f;
  float sv = pv0 + pv1;
  #pragma unroll
  for (int off=32; off; off>>=1) sv += __shfl_xor(sv, off);
  if (lane==0) red[4+w] = sv;
  __syncthreads();
  float inv = 1.0f/(red[4]+red[5]+red[6]+red[7]);
  ps[tid] = pv0*inv;
  if (tid < 144) ps[tid+256] = pv1*inv;
  __syncthreads();
  // ctx chunk: 128 h, two s-halves
  int hloc = tid & 127, sh = tid >> 7;
  int h = hc*128 + hloc;
  const float* mq = mem + (size_t)b*204800 + h;
  float acc = 0.0f;
  {
    const float* mqs = mq + (size_t)sh*200*512;
    const float* pss = &ps[sh*200];
    #pragma unroll 8
    for (int s=0;s<200;s++) acc += pss[s]*mqs[(size_t)s*512];
  }
  if (sh==1) tmp[hloc] = acc;
  __syncthreads();
  if (sh==0){
    float v = acc + tmp[hloc];
    ctxb[b*512+h] = v;
    ctxa[(size_t)r*512+h] = v;
  }
  if (hc==0){
    for (int s=tid; s<400; s+=256){
      float a = ps[s];
      out[OFF_A + (size_t)r*400 + s] = a;
      float cv = cov[b*400+s];
      out[OFF_C + (size_t)r*400 + s] = cv;
      cov[b*400+s] = cv + a;
    }
  }
}

// ---------------- logit_in = tanh([h_all|ctx_all]@W_cat^T + b_cat) -> bf16 (MFMA) ----
// grid dim3(8,4): m0 = x*128 (1024 rows), n0 = y*128 (512 cols); K=1024 in 32 steps
__global__ __launch_bounds__(256) void k_logitin(const float* __restrict__ hall,
    const float* __restrict__ ctxa, const float* __restrict__ W_cat,
    const float* __restrict__ b_cat, __hip_bfloat16* __restrict__ lib) {
  __shared__ short As[4096];
  __shared__ short Bs[4096];
  int tid = threadIdx.x;
  int m0 = blockIdx.x*128, n0 = blockIdx.y*128;
  int w = tid>>6, lane = tid&63;
  int wr = w>>1, wc = w&1;
  int lr = lane&15, kg2 = lane>>4;

  int srow = tid>>1;
  int half = tid&1;
  int wo0 = lds_off(srow, half*2), wo1 = lds_off(srow, half*2+1);

  int raoff[4], rboff[4];
  #pragma unroll
  for (int q=0;q<4;q++){
    raoff[q] = lds_off(wr*64 + q*16 + lr, kg2);
    rboff[q] = lds_off(wc*64 + q*16 + lr, kg2);
  }

  facc4 acc[4][4] = {};
  for (int ks=0; ks<32; ks++){
    int k0 = ks*32 + half*16;
    const float* arow = (k0 < 512) ? (hall + (size_t)(m0+srow)*512 + k0)
                                   : (ctxa + (size_t)(m0+srow)*512 + k0 - 512);
    const float* brow = W_cat + (size_t)(n0+srow)*1024 + k0;
    short a16[16], b16[16];
    #pragma unroll
    for (int q=0;q<16;q+=4){
      float4 av = *(const float4*)(arow+q);
      float4 bv = *(const float4*)(brow+q);
      a16[q+0]=f2bf(av.x); a16[q+1]=f2bf(av.y); a16[q+2]=f2bf(av.z); a16[q+3]=f2bf(av.w);
      b16[q+0]=f2bf(bv.x); b16[q+1]=f2bf(bv.y); b16[q+2]=f2bf(bv.z); b16[q+3]=f2bf(bv.w);
    }
    __syncthreads();
    *(bfrag8*)((char*)As + wo0) = *(const bfrag8*)&a16[0];
    *(bfrag8*)((char*)As + wo1) = *(const bfrag8*)&a16[8];
    *(bfrag8*)((char*)Bs + wo0) = *(const bfrag8*)&b16[0];
    *(bfrag8*)((char*)Bs + wo1) = *(const bfrag8*)&b16[8];
    __syncthreads();
    bfrag8 af[4], bf[4];
    #pragma unroll
    for (int q=0;q<4;q++){
      af[q] = *(const bfrag8*)((char*)As + raoff[q]);
      bf[q] = *(const bfrag8*)((char*)Bs + rboff[q]);
    }
    #pragma unroll
    for (int mi=0;mi<4;mi++)
      #pragma unroll
      for (int ni=0;ni<4;ni++)
        acc[mi][ni] = __builtin_amdgcn_mfma_f32_16x16x32_bf16(af[mi], bf[ni], acc[mi][ni], 0,0,0);
  }

  #pragma unroll
  for (int mi=0;mi<4;mi++){
    int row = m0 + wr*64 + mi*16 + kg2*4;
    #pragma unroll
    for (int ni=0;ni<4;ni++){
      int col = n0 + wc*64 + ni*16 + lr;
      float bc = b_cat[col];
      #pragma unroll
      for (int q=0;q<4;q++){
        float v = tanhf(acc[mi][ni][q] + bc);
        lib[(size_t)(row+q)*512 + col] = __float2bfloat16(v);
      }
    }
  }
}

// ---------------- logits = logit_in @ W_log^T + b_log (bf16 MFMA, 128x128 tile) -------
__global__ __launch_bounds__(256) void k_logits(const __hip_bfloat16* __restrict__ Ab,
    const __hip_bfloat16* __restrict__ Wb, const float* __restrict__ b_log,
    float* __restrict__ out) {
  __shared__ short As[4096];
  __shared__ short Bs[4096];
  int tid = threadIdx.x;
  int m0 = blockIdx.x*128, n0 = blockIdx.y*128;
  int w = tid>>6, lane = tid&63;
  int wr = w>>1, wc = w&1;
  int lr = lane&15, kg2 = lane>>4;
  const short* A = (const short*)Ab;
  const short* W = (const short*)Wb;

  int srow = tid>>1;
  int ss   = (tid&1)*2;
  const short* ga = A + (size_t)(m0+srow)*512 + ss*8;
  const short* gw = W + (size_t)(n0+srow)*512 + ss*8;
  int wo0 = lds_off(srow, ss), wo1 = lds_off(srow, ss+1);

  int raoff[4], rboff[4];
  #pragma unroll
  for (int q=0;q<4;q++){
    raoff[q] = lds_off(wr*64 + q*16 + lr, kg2);
    rboff[q] = lds_off(wc*64 + q*16 + lr, kg2);
  }

  facc4 acc[4][4] = {};
  bfrag8 ra0 = *(const bfrag8*)(ga);
  bfrag8 ra1 = *(const bfrag8*)(ga+8);
  bfrag8 rb0 = *(const bfrag8*)(gw);
  bfrag8 rb1 = *(const bfrag8*)(gw+8);

  for (int i=0;i<16;i++){
    __syncthreads();
    *(bfrag8*)((char*)As + wo0) = ra0;
    *(bfrag8*)((char*)As + wo1) = ra1;
    *(bfrag8*)((char*)Bs + wo0) = rb0;
    *(bfrag8*)((char*)Bs + wo1) = rb1;
    __syncthreads();
    if (i<15){
      ga += 32; gw += 32;
      ra0 = *(const bfrag8*)(ga);
      ra1 = *(const bfrag8*)(ga+8);
      rb0 = *(const bfrag8*)(gw);
      rb1 = *(const bfrag8*)(gw+8);
    }
    bfrag8 af[4], bf[4];
    #pragma unroll
    for (int q=0;q<4;q++){
      af[q] = *(const bfrag8*)((char*)As + raoff[q]);
      bf[q] = *(const bfrag8*)((char*)Bs + rboff[q]);
    }
    #pragma unroll
    for (int mi=0;mi<4;mi++)
      #pragma unroll
      for (int ni=0;ni<4;ni++)
        acc[mi][ni] = __builtin_amdgcn_mfma_f32_16x16x32_bf16(af[mi], bf[ni], acc[mi][ni], 0,0,0);
  }

  #pragma unroll
  for (int mi=0;mi<4;mi++){
    int row = m0 + wr*64 + mi*16 + kg2*4;
    #pragma unroll
    for (int ni=0;ni<4;ni++){
      int col = n0 + wc*64 + ni*16 + lr;
      float bl = b_log[col];
      #pragma unroll
      for (int q=0;q<4;q++){
        float v = acc[mi][ni][q] + bl;
        out[(size_t)(row+q)*32050 + col] = (v == 0.0f) ? -INF_F : v;
      }
    }
  }
}

// ---------------- scatter-max of energies into extended logits (+ OOV fill) ---------
__global__ __launch_bounds__(128) void k_scatter(const int* __restrict__ ext_src,
    float* __restrict__ out) {
  __shared__ int tok[400];
  __shared__ float ev[400];
  int rr = blockIdx.x;
  int b = rr & 31;
  int tid = threadIdx.x;
  if (tid < 50) out[(size_t)rr*32050 + 32000 + tid] = -INF_F;
  for (int s=tid; s<400; s+=128){
    tok[s] = ext_src[b*400+s];
    ev[s]  = out[OFF_E + (size_t)rr*400 + s];
  }
  __syncthreads();
  for (int s=tid; s<400; s+=128){
    int tk = tok[s];
    float m = ev[s];
    bool first = true;
    for (int s2=0; s2<400; s2++){
      if (tok[s2]==tk){
        if (s2 < s) first=false;
        m = fmaxf(m, ev[s2]);
      }
    }
    if (first && m != -INF_F){
      size_t idx = (size_t)rr*32050 + tk;
      float wv = out[idx];
      float extv = (wv == -INF_F) ? 0.0f : wv;
      float nv = extv + m;
      out[idx] = (nv == 0.0f) ? -INF_F : nv;
    }
  }
}

extern "C" void kernel_launch(void* const* d_in, const int* in_sizes, int n_in,
                              void* d_out, int out_size, void* d_ws, size_t ws_size,
                              hipStream_t stream) {
  const float* trg   = (const float*)d_in[0];
  const int*   ext   = (const int*)  d_in[1];
  const float* inits = (const float*)d_in[2];
  const float* enc   = (const float*)d_in[3];
  const int*   emask = (const int*)  d_in[4];
  const float* W_enc = (const float*)d_in[5];
  const float* b_enc = (const float*)d_in[6];
  const float* W_red = (const float*)d_in[7];
  const float* b_red = (const float*)d_in[8];
  const float* W_ih  = (const float*)d_in[9];
  const float* W_hh  = (const float*)d_in[10];
  const float* b_ih  = (const float*)d_in[11];
  const float* b_hh  = (const float*)d_in[12];
  const float* W_cat = (const float*)d_in[13];
  const float* b_cat = (const float*)d_in[14];
  const float* W_log = (const float*)d_in[15];
  const float* b_log = (const float*)d_in[16];
  float* out = (float*)d_out;
  float* ws  = (float*)d_ws;

  float* mem   = ws + 0ull;          // 6,553,600
  float* Wg    = ws + 6553600ull;    // 2,097,152
  float* Wct   = ws + 8650752ull;    // 1,662,976
  float* Gemb  = ws + 10313728ull;   // 2,097,152
  float* bcomb = ws + 12410880ull;   // 2,048
  float* hbuf  = ws + 12412928ull;   // 16,384
  float* c0    = ws + 12429312ull;   // 16,384
  float* c1    = ws + 12445696ull;   // 16,384
  float* ctxb  = ws + 12462080ull;   // 16,384
  float* hall  = ws + 12478464ull;   // 524,288
  float* ctxa  = ws + 13002752ull;   // 524,288
  float* cov   = ws + 13527040ull;   // 12,800
  float* part  = ws + 13539840ull;   // 524,288
  __hip_bfloat16* lib = (__hip_bfloat16*)(ws + 14590464ull);   // 262,144 floats
  __hip_bfloat16* wlb = (__hip_bfloat16*)(ws + 14852608ull);   // 8,192,000 floats
  // hi/lo split scratch OVERLAPS wlb (dead until k_wlogconv, which runs after k_memories)
  short* ehi = (short*)(ws + 14852608ull);   // 6,553,600 shorts
  short* elo = ehi + 6553600;                // 6,553,600 shorts
  short* whi = ehi + 13107200;               // 262,144 shorts
  short* wlo = ehi + 13369344;               // 262,144 shorts

  k_init<<<64,256,0,stream>>>(inits, hbuf, c0, ctxb, cov);
  k_bcombo<<<8,256,0,stream>>>(W_ih, b_red, b_ih, b_hh, bcomb);
  k_wcombo<<<dim3(13,32),256,0,stream>>>(W_ih, W_red, Wct);
  k_gemb<<<dim3(32,16),256,0,stream>>>(trg, Wct, bcomb, Gemb);
  k_wgpack<<<8192,256,0,stream>>>(Wct, W_hh, Wg);
  k_convsplit<<<6656,256,0,stream>>>(enc, W_enc, ehi, elo, whi, wlo);
  k_memories<<<dim3(100,4),256,0,stream>>>(ehi, elo, whi, wlo, b_enc, mem);
  k_wlogconv<<<16000,256,0,stream>>>(W_log, wlb);

  for (int t=0;t<32;t++){
    const float* c_in = (t&1) ? c1 : c0;
    float* c_out      = (t&1) ? c0 : c1;
    k_gates<<<dim3(8,16),256,0,stream>>>(ctxb, hbuf, Wg, part);
    k_lstm_energy<<<256,256,0,stream>>>(part, Gemb, c_in, c_out, hbuf, hall,
                                        mem, emask, out, t);
    k_ctx<<<128,256,0,stream>>>(out, mem, ctxb, ctxa, cov, t);
  }

  k_logitin<<<dim3(8,4),256,0,stream>>>(hall, ctxa, W_cat, b_cat, lib);
  k_logits<<<dim3(8,250),256,0,stream>>>(lib, wlb, b_log, out);
  k_scatter<<<1024,128,0,stream>>>(ext, out);
}

// Round 8
// 1424.406 us; speedup vs baseline: 10.7564x; 1.0476x over previous
//
#include <hip/hip_runtime.h>
#include <hip/hip_bf16.h>

#define INF_F 1000000000000.0f

typedef __attribute__((ext_vector_type(8))) short bfrag8;
typedef __attribute__((ext_vector_type(4))) float facc4;
typedef __attribute__((ext_vector_type(4))) short short4v;

__device__ __forceinline__ float sigf(float x){ return 1.0f/(1.0f + expf(-x)); }
__device__ __forceinline__ short f2bf(float f){
  __hip_bfloat16 h = __float2bfloat16(f);
  return *reinterpret_cast<short*>(&h);
}
__device__ __forceinline__ float bf2f(short s){
  unsigned u = ((unsigned)(unsigned short)s) << 16;
  return *reinterpret_cast<float*>(&u);
}

// out-region offsets (floats)
#define OFF_LOG 0ull
#define OFF_A   32819200ull
#define OFF_C   33228800ull
#define OFF_E   33638400ull

// ---------------- init ----------------
__global__ __launch_bounds__(256) void k_init(const float* __restrict__ init_s,
    float* __restrict__ hbuf, float* __restrict__ c0, float* __restrict__ ctxb,
    float* __restrict__ cov) {
  int i = blockIdx.x*256 + threadIdx.x;
  if (i < 32*512) { float v = init_s[i]; hbuf[i]=v; c0[i]=v; ctxb[i]=0.0f; }
  if (i < 32*400) cov[i] = 0.0f;
}

// ---------------- b_combo = W_ih@b_red + b_ih + b_hh ----------------
__global__ __launch_bounds__(256) void k_bcombo(const float* __restrict__ W_ih,
    const float* __restrict__ b_red, const float* __restrict__ b_ih,
    const float* __restrict__ b_hh, float* __restrict__ bcomb) {
  int j = blockIdx.x*256 + threadIdx.x;
  if (j >= 2048) return;
  float acc = b_ih[j] + b_hh[j];
  for (int m=0;m<300;m++) acc += W_ih[j*300+m]*b_red[m];
  bcomb[j] = acc;
}

// ---------------- Wct[2048][812] = W_ih[2048x300] @ W_red[300x812] ----------------
__global__ __launch_bounds__(256) void k_wcombo(const float* __restrict__ W_ih,
    const float* __restrict__ W_red, float* __restrict__ Wct) {
  __shared__ float As[16][68];
  __shared__ float Bs[16][68];
  int tid = threadIdx.x;
  int m0 = blockIdx.y*64, n0 = blockIdx.x*64;
  int rl = tid>>2, kq = (tid&3)*4;
  int kl = tid>>4, c4 = (tid&15)*4;
  int tx = tid&15, ty = tid>>4;
  float acc[4][4]={};
  for (int kk=0;kk<300;kk+=16){
    #pragma unroll
    for (int q=0;q<4;q++){
      int kg = kk+kq+q;
      As[kq+q][rl] = (kg<300) ? W_ih[(size_t)(m0+rl)*300 + kg] : 0.0f;
    }
    #pragma unroll
    for (int q=0;q<4;q++){
      int c = n0 + c4 + q;
      Bs[kl][c4+q] = (kk+kl<300 && c<812) ? W_red[(size_t)(kk+kl)*812 + c] : 0.0f;
    }
    __syncthreads();
    #pragma unroll
    for (int k=0;k<16;k++){
      const float* ap=&As[k][ty*4]; const float* bp=&Bs[k][tx*4];
      #pragma unroll
      for (int i=0;i<4;i++)
        #pragma unroll
        for (int j=0;j<4;j++) acc[i][j] += ap[i]*bp[j];
    }
    __syncthreads();
  }
  #pragma unroll
  for (int i=0;i<4;i++)
    #pragma unroll
    for (int j=0;j<4;j++){
      int row = m0+ty*4+i, col = n0+tx*4+j;
      if (col<812) Wct[(size_t)row*812 + col] = acc[i][j];
    }
}

// ---------------- G_emb[1024][2048] = emb[1024x300] @ Wct[:,0:300]^T + b_combo --------
__global__ __launch_bounds__(256) void k_gemb(const float* __restrict__ trg,
    const float* __restrict__ Wct, const float* __restrict__ bcomb,
    float* __restrict__ Gemb) {
  __shared__ float As[16][68];
  __shared__ float Bs[16][68];
  int tid = threadIdx.x;
  int m0 = blockIdx.y*64, n0 = blockIdx.x*64;
  int rl = tid>>2, kq = (tid&3)*4;
  int tx = tid&15, ty = tid>>4;
  float acc[4][4]={};
  int r = m0 + rl;
  const float* arow = trg + (size_t)(r&31)*9600 + (size_t)(r>>5)*300;
  for (int kk=0;kk<300;kk+=16){
    #pragma unroll
    for (int q=0;q<4;q++){
      int kg = kk+kq+q;
      As[kq+q][rl] = (kg<300) ? arow[kg] : 0.0f;
      Bs[kq+q][rl] = (kg<300) ? Wct[(size_t)(n0+rl)*812 + kg] : 0.0f;
    }
    __syncthreads();
    #pragma unroll
    for (int k=0;k<16;k++){
      const float* ap=&As[k][ty*4]; const float* bp=&Bs[k][tx*4];
      #pragma unroll
      for (int i=0;i<4;i++)
        #pragma unroll
        for (int j=0;j<4;j++) acc[i][j] += ap[i]*bp[j];
    }
    __syncthreads();
  }
  #pragma unroll
  for (int i=0;i<4;i++)
    #pragma unroll
    for (int j=0;j<4;j++){
      int rr = m0+ty*4+i, col = n0+tx*4+j;
      Gemb[(size_t)rr*2048 + col] = acc[i][j] + bcomb[col];
    }
}

// ---------------- Wg[1024][2048]: k<512 -> Wct[:,300+k]^T ; k>=512 -> W_hh^T ----------
__global__ __launch_bounds__(256) void k_wgpack(const float* __restrict__ Wct,
    const float* __restrict__ W_hh, float* __restrict__ Wg) {
  int idx = blockIdx.x*256 + threadIdx.x;
  if (idx >= 1024*2048) return;
  int k = idx >> 11, j = idx & 2047;
  Wg[idx] = (k < 512) ? Wct[(size_t)j*812 + 300 + k] : W_hh[(size_t)j*512 + (k-512)];
}

// ---------------- split enc & W_enc into bf16 hi/lo pairs ----------------
__global__ __launch_bounds__(256) void k_convsplit(const float* __restrict__ enc,
    const float* __restrict__ W_enc, short* __restrict__ ehi, short* __restrict__ elo,
    short* __restrict__ whi, short* __restrict__ wlo) {
  int i4 = blockIdx.x*256 + threadIdx.x;
  const float* src; short* dhi; short* dlo; size_t off;
  if (i4 < 1638400) { src = enc;   dhi = ehi; dlo = elo; off = (size_t)i4*4; }
  else { int j4 = i4 - 1638400; if (j4 >= 65536) return;
         src = W_enc; dhi = whi; dlo = wlo; off = (size_t)j4*4; }
  float4 v = *(const float4*)(src + off);
  float f[4] = {v.x, v.y, v.z, v.w};
  short4v h, l;
  #pragma unroll
  for (int q=0;q<4;q++){
    short hb = f2bf(f[q]);
    float r = f[q] - bf2f(hb);
    h[q] = hb; l[q] = f2bf(r);
  }
  *(short4v*)(dhi + off) = h;
  *(short4v*)(dlo + off) = l;
}

// swizzled LDS byte offset: row in [0,128), slot in [0,4) (16B granules of a 64B row)
__device__ __forceinline__ int lds_off(int row, int slot) {
  return (row<<6) + (((slot ^ ((row>>1)&3))&3)<<4);
}

// ---------------- memories = enc @ W_enc^T + b_enc  (split-precision 3xbf16 MFMA) ----
__global__ __launch_bounds__(256) void k_memories(const short* __restrict__ Ahg,
    const short* __restrict__ Alg, const short* __restrict__ Bhg,
    const short* __restrict__ Blg, const float* __restrict__ bias,
    float* __restrict__ mem) {
  __shared__ short Ah[4096];
  __shared__ short Al[4096];
  __shared__ short Bh[4096];
  __shared__ short Bl[4096];
  int tid = threadIdx.x;
  int m0 = blockIdx.x*128, n0 = blockIdx.y*128;
  int w = tid>>6, lane = tid&63;
  int wr = w>>1, wc = w&1;
  int lr = lane&15, kg2 = lane>>4;

  int srow = tid>>1;
  int ss   = (tid&1)*2;
  const short* gah = Ahg + (size_t)(m0+srow)*512 + ss*8;
  const short* gal = Alg + (size_t)(m0+srow)*512 + ss*8;
  const short* gbh = Bhg + (size_t)(n0+srow)*512 + ss*8;
  const short* gbl = Blg + (size_t)(n0+srow)*512 + ss*8;
  int wo0 = lds_off(srow, ss), wo1 = lds_off(srow, ss+1);

  int raoff[4], rboff[4];
  #pragma unroll
  for (int q=0;q<4;q++){
    raoff[q] = lds_off(wr*64 + q*16 + lr, kg2);
    rboff[q] = lds_off(wc*64 + q*16 + lr, kg2);
  }

  facc4 acc[4][4] = {};
  bfrag8 rah0 = *(const bfrag8*)(gah);
  bfrag8 rah1 = *(const bfrag8*)(gah+8);
  bfrag8 ral0 = *(const bfrag8*)(gal);
  bfrag8 ral1 = *(const bfrag8*)(gal+8);
  bfrag8 rbh0 = *(const bfrag8*)(gbh);
  bfrag8 rbh1 = *(const bfrag8*)(gbh+8);
  bfrag8 rbl0 = *(const bfrag8*)(gbl);
  bfrag8 rbl1 = *(const bfrag8*)(gbl+8);

  for (int i=0;i<16;i++){
    __syncthreads();
    *(bfrag8*)((char*)Ah + wo0) = rah0;
    *(bfrag8*)((char*)Ah + wo1) = rah1;
    *(bfrag8*)((char*)Al + wo0) = ral0;
    *(bfrag8*)((char*)Al + wo1) = ral1;
    *(bfrag8*)((char*)Bh + wo0) = rbh0;
    *(bfrag8*)((char*)Bh + wo1) = rbh1;
    *(bfrag8*)((char*)Bl + wo0) = rbl0;
    *(bfrag8*)((char*)Bl + wo1) = rbl1;
    __syncthreads();
    if (i<15){
      gah += 32; gal += 32; gbh += 32; gbl += 32;
      rah0 = *(const bfrag8*)(gah);
      rah1 = *(const bfrag8*)(gah+8);
      ral0 = *(const bfrag8*)(gal);
      ral1 = *(const bfrag8*)(gal+8);
      rbh0 = *(const bfrag8*)(gbh);
      rbh1 = *(const bfrag8*)(gbh+8);
      rbl0 = *(const bfrag8*)(gbl);
      rbl1 = *(const bfrag8*)(gbl+8);
    }
    bfrag8 afh[4], afl[4], bfh[4], bfl[4];
    #pragma unroll
    for (int q=0;q<4;q++){
      afh[q] = *(const bfrag8*)((char*)Ah + raoff[q]);
      afl[q] = *(const bfrag8*)((char*)Al + raoff[q]);
      bfh[q] = *(const bfrag8*)((char*)Bh + rboff[q]);
      bfl[q] = *(const bfrag8*)((char*)Bl + rboff[q]);
    }
    #pragma unroll
    for (int mi=0;mi<4;mi++)
      #pragma unroll
      for (int ni=0;ni<4;ni++){
        acc[mi][ni] = __builtin_amdgcn_mfma_f32_16x16x32_bf16(afl[mi], bfh[ni], acc[mi][ni], 0,0,0);
        acc[mi][ni] = __builtin_amdgcn_mfma_f32_16x16x32_bf16(afh[mi], bfl[ni], acc[mi][ni], 0,0,0);
        acc[mi][ni] = __builtin_amdgcn_mfma_f32_16x16x32_bf16(afh[mi], bfh[ni], acc[mi][ni], 0,0,0);
      }
  }

  #pragma unroll
  for (int mi=0;mi<4;mi++){
    int row = m0 + wr*64 + mi*16 + kg2*4;
    #pragma unroll
    for (int ni=0;ni<4;ni++){
      int col = n0 + wc*64 + ni*16 + lr;
      float bl = bias[col];
      #pragma unroll
      for (int q=0;q<4;q++)
        mem[(size_t)(row+q)*512 + col] = acc[mi][ni][q] + bl;
    }
  }
}

// ---------------- W_log -> bf16 ----------------
__global__ __launch_bounds__(256) void k_wlogconv(const float* __restrict__ W_log,
    __hip_bfloat16* __restrict__ wlb) {
  int i4 = blockIdx.x*256 + threadIdx.x;
  if (i4 >= 32000*512/4) return;
  const float4 v = *(const float4*)(W_log + (size_t)i4*4);
  size_t o = (size_t)i4*4;
  wlb[o+0] = __float2bfloat16(v.x); wlb[o+1] = __float2bfloat16(v.y);
  wlb[o+2] = __float2bfloat16(v.z); wlb[o+3] = __float2bfloat16(v.w);
}

// ---------------- per-step: gates partial GEMM ----------------
__global__ __launch_bounds__(256) void k_gates(const float* __restrict__ ctxb,
    const float* __restrict__ hbuf, const float* __restrict__ Wg,
    float* __restrict__ partials) {
  __shared__ float yh_s[128][32];
  int ks = blockIdx.x;
  int rc = blockIdx.y;
  int tid = threadIdx.x;
  const float* side = (ks < 4) ? ctxb : hbuf;
  int kbase = (ks & 3) * 128;
  {
    int b_l = tid >> 3, kq0 = (tid & 7) * 16;
    const float* src = side + (size_t)b_l*512 + kbase + kq0;
    #pragma unroll
    for (int q=0;q<16;q+=4){
      float4 v = *(const float4*)(src + q);
      yh_s[kq0+q+0][b_l]=v.x; yh_s[kq0+q+1][b_l]=v.y;
      yh_s[kq0+q+2][b_l]=v.z; yh_s[kq0+q+3][b_l]=v.w;
    }
  }
  __syncthreads();
  int tr = tid & 31, bg = tid >> 5;
  int row0 = rc*128 + tr*4;
  float acc[4][4] = {};
  const float* wp = Wg + (size_t)(ks*128)*2048 + row0;
  #pragma unroll 8
  for (int k=0;k<128;k++){
    float4 w = *(const float4*)(wp + (size_t)k*2048);
    float4 y = *(const float4*)&yh_s[k][bg*4];
    acc[0][0]+=w.x*y.x; acc[0][1]+=w.x*y.y; acc[0][2]+=w.x*y.z; acc[0][3]+=w.x*y.w;
    acc[1][0]+=w.y*y.x; acc[1][1]+=w.y*y.y; acc[1][2]+=w.y*y.z; acc[1][3]+=w.y*y.w;
    acc[2][0]+=w.z*y.x; acc[2][1]+=w.z*y.y; acc[2][2]+=w.z*y.z; acc[2][3]+=w.z*y.w;
    acc[3][0]+=w.w*y.x; acc[3][1]+=w.w*y.y; acc[3][2]+=w.w*y.z; acc[3][3]+=w.w*y.w;
  }
  #pragma unroll
  for (int j=0;j<4;j++){
    float4 o; o.x=acc[0][j]; o.y=acc[1][j]; o.z=acc[2][j]; o.w=acc[3][j];
    *(float4*)(partials + (size_t)(ks*32 + bg*4 + j)*2048 + row0) = o;
  }
}

// ---------------- per-step: partial reduce + LSTM (redundant) + energy chunk --------
__global__ __launch_bounds__(256) void k_lstm_energy(const float* __restrict__ part,
    const float* __restrict__ Gemb,
    const float* __restrict__ c_in, float* __restrict__ c_out,
    float* __restrict__ hbuf, float* __restrict__ hall,
    const float* __restrict__ mem, const int* __restrict__ emask,
    float* __restrict__ out, int t) {
  __shared__ float hl[512];
  int blk = blockIdx.x, tid = threadIdx.x;
  int b = blk & 31, sc = blk >> 5;
  int r = t*32 + b;
  int lane = tid & 63, w = tid >> 6;
  const float* gp = Gemb + (size_t)r*2048;
  #pragma unroll
  for (int jj=0; jj<2; jj++){
    int j = tid + jj*256;
    float g[4];
    #pragma unroll
    for (int gi=0; gi<4; gi++){
      int row = gi*512 + j;
      float v = gp[row];
      #pragma unroll
      for (int ks=0; ks<8; ks++)
        v += part[(size_t)(ks*32+b)*2048 + row];
      g[gi] = v;
    }
    float cp = c_in[b*512+j];
    float cn = sigf(g[1])*cp + sigf(g[0])*tanhf(g[2]);
    float hn = sigf(g[3])*tanhf(cn);
    hl[j] = hn;
    if (sc==0){
      c_out[b*512+j]=cn; hbuf[b*512+j]=hn; hall[(size_t)r*512+j]=hn;
    }
  }
  __syncthreads();
  float4 h0 = *(const float4*)&hl[lane*8];
  float4 h1 = *(const float4*)&hl[lane*8+4];
  const float* mb = mem + (size_t)b*204800;
  const int* em = emask + b*400;
  for (int i=0;i<13;i++){
    int s_l = i*4 + w;
    if (s_l < 50){
      int s = sc*50 + s_l;
      const float4* mp = (const float4*)(mb + (size_t)s*512 + lane*8);
      float4 m0 = mp[0], m1 = mp[1];
      float acc = h0.x*m0.x + h0.y*m0.y + h0.z*m0.z + h0.w*m0.w
                + h1.x*m1.x + h1.y*m1.y + h1.z*m1.z + h1.w*m1.w;
      #pragma unroll
      for (int off=32; off; off>>=1) acc += __shfl_xor(acc, off);
      if (lane==0){
        out[OFF_E + (size_t)r*400 + s] = (em[s]==0) ? -INF_F : acc;
      }
    }
  }
}

// ---------------- per-step: softmax (redundant) + ctx chunk + attn/cov -------------
__global__ __launch_bounds__(256) void k_ctx(float* __restrict__ out,
    const float* __restrict__ mem, float* __restrict__ ctxb, float* __restrict__ ctxa,
    float* __restrict__ cov, int t) {
  __shared__ float ps[400];
  __shared__ float red[8];
  __shared__ float tmp[128];
  int blk = blockIdx.x, tid = threadIdx.x;
  int b = blk & 31, hc = blk >> 5;
  int r = t*32 + b;
  int lane = tid & 63, w = tid >> 6;
  float e0 = out[OFF_E + (size_t)r*400 + tid];
  float e1 = (tid < 144) ? out[OFF_E + (size_t)r*400 + tid + 256] : -3.4e38f;
  float lm = fmaxf(e0, e1);
  #pragma unroll
  for (int off=32; off; off>>=1) lm = fmaxf(lm, __shfl_xor(lm, off));
  if (lane==0) red[w] = lm;
  __syncthreads();
  float m = fmaxf(fmaxf(red[0],red[1]), fmaxf(red[2],red[3]));
  float pv0 = expf(e0 - m);
  float pv1 = (tid < 144) ? expf(e1 - m) : 0.0f;
  float sv = pv0 + pv1;
  #pragma unroll
  for (int off=32; off; off>>=1) sv += __shfl_xor(sv, off);
  if (lane==0) red[4+w] = sv;
  __syncthreads();
  float inv = 1.0f/(red[4]+red[5]+red[6]+red[7]);
  ps[tid] = pv0*inv;
  if (tid < 144) ps[tid+256] = pv1*inv;
  __syncthreads();
  // ctx chunk: 128 h, two s-halves
  int hloc = tid & 127, sh = tid >> 7;
  int h = hc*128 + hloc;
  const float* mq = mem + (size_t)b*204800 + h;
  float acc = 0.0f;
  {
    const float* mqs = mq + (size_t)sh*200*512;
    const float* pss = &ps[sh*200];
    #pragma unroll 8
    for (int s=0;s<200;s++) acc += pss[s]*mqs[(size_t)s*512];
  }
  if (sh==1) tmp[hloc] = acc;
  __syncthreads();
  if (sh==0){
    float v = acc + tmp[hloc];
    ctxb[b*512+h] = v;
    ctxa[(size_t)r*512+h] = v;
  }
  if (hc==0){
    for (int s=tid; s<400; s+=256){
      float a = ps[s];
      out[OFF_A + (size_t)r*400 + s] = a;
      float cv = cov[b*400+s];
      out[OFF_C + (size_t)r*400 + s] = cv;
      cov[b*400+s] = cv + a;
    }
  }
}

// ---------------- logit_in = tanh([h_all|ctx_all]@W_cat^T + b_cat) -> bf16 (MFMA) ----
__global__ __launch_bounds__(256) void k_logitin(const float* __restrict__ hall,
    const float* __restrict__ ctxa, const float* __restrict__ W_cat,
    const float* __restrict__ b_cat, __hip_bfloat16* __restrict__ lib) {
  __shared__ short As[4096];
  __shared__ short Bs[4096];
  int tid = threadIdx.x;
  int m0 = blockIdx.x*128, n0 = blockIdx.y*128;
  int w = tid>>6, lane = tid&63;
  int wr = w>>1, wc = w&1;
  int lr = lane&15, kg2 = lane>>4;

  int srow = tid>>1;
  int half = tid&1;
  int wo0 = lds_off(srow, half*2), wo1 = lds_off(srow, half*2+1);

  int raoff[4], rboff[4];
  #pragma unroll
  for (int q=0;q<4;q++){
    raoff[q] = lds_off(wr*64 + q*16 + lr, kg2);
    rboff[q] = lds_off(wc*64 + q*16 + lr, kg2);
  }

  facc4 acc[4][4] = {};
  for (int ks=0; ks<32; ks++){
    int k0 = ks*32 + half*16;
    const float* arow = (k0 < 512) ? (hall + (size_t)(m0+srow)*512 + k0)
                                   : (ctxa + (size_t)(m0+srow)*512 + k0 - 512);
    const float* brow = W_cat + (size_t)(n0+srow)*1024 + k0;
    short a16[16], b16[16];
    #pragma unroll
    for (int q=0;q<16;q+=4){
      float4 av = *(const float4*)(arow+q);
      float4 bv = *(const float4*)(brow+q);
      a16[q+0]=f2bf(av.x); a16[q+1]=f2bf(av.y); a16[q+2]=f2bf(av.z); a16[q+3]=f2bf(av.w);
      b16[q+0]=f2bf(bv.x); b16[q+1]=f2bf(bv.y); b16[q+2]=f2bf(bv.z); b16[q+3]=f2bf(bv.w);
    }
    __syncthreads();
    *(bfrag8*)((char*)As + wo0) = *(const bfrag8*)&a16[0];
    *(bfrag8*)((char*)As + wo1) = *(const bfrag8*)&a16[8];
    *(bfrag8*)((char*)Bs + wo0) = *(const bfrag8*)&b16[0];
    *(bfrag8*)((char*)Bs + wo1) = *(const bfrag8*)&b16[8];
    __syncthreads();
    bfrag8 af[4], bf[4];
    #pragma unroll
    for (int q=0;q<4;q++){
      af[q] = *(const bfrag8*)((char*)As + raoff[q]);
      bf[q] = *(const bfrag8*)((char*)Bs + rboff[q]);
    }
    #pragma unroll
    for (int mi=0;mi<4;mi++)
      #pragma unroll
      for (int ni=0;ni<4;ni++)
        acc[mi][ni] = __builtin_amdgcn_mfma_f32_16x16x32_bf16(af[mi], bf[ni], acc[mi][ni], 0,0,0);
  }

  #pragma unroll
  for (int mi=0;mi<4;mi++){
    int row = m0 + wr*64 + mi*16 + kg2*4;
    #pragma unroll
    for (int ni=0;ni<4;ni++){
      int col = n0 + wc*64 + ni*16 + lr;
      float bc = b_cat[col];
      #pragma unroll
      for (int q=0;q<4;q++){
        float v = tanhf(acc[mi][ni][q] + bc);
        lib[(size_t)(row+q)*512 + col] = __float2bfloat16(v);
      }
    }
  }
}

// ---------------- logits = logit_in @ W_log^T + b_log (bf16 MFMA, 128x128 tile) -------
__global__ __launch_bounds__(256) void k_logits(const __hip_bfloat16* __restrict__ Ab,
    const __hip_bfloat16* __restrict__ Wb, const float* __restrict__ b_log,
    float* __restrict__ out) {
  __shared__ short As[4096];
  __shared__ short Bs[4096];
  int tid = threadIdx.x;
  int m0 = blockIdx.x*128, n0 = blockIdx.y*128;
  int w = tid>>6, lane = tid&63;
  int wr = w>>1, wc = w&1;
  int lr = lane&15, kg2 = lane>>4;
  const short* A = (const short*)Ab;
  const short* W = (const short*)Wb;

  int srow = tid>>1;
  int ss   = (tid&1)*2;
  const short* ga = A + (size_t)(m0+srow)*512 + ss*8;
  const short* gw = W + (size_t)(n0+srow)*512 + ss*8;
  int wo0 = lds_off(srow, ss), wo1 = lds_off(srow, ss+1);

  int raoff[4], rboff[4];
  #pragma unroll
  for (int q=0;q<4;q++){
    raoff[q] = lds_off(wr*64 + q*16 + lr, kg2);
    rboff[q] = lds_off(wc*64 + q*16 + lr, kg2);
  }

  facc4 acc[4][4] = {};
  bfrag8 ra0 = *(const bfrag8*)(ga);
  bfrag8 ra1 = *(const bfrag8*)(ga+8);
  bfrag8 rb0 = *(const bfrag8*)(gw);
  bfrag8 rb1 = *(const bfrag8*)(gw+8);

  for (int i=0;i<16;i++){
    __syncthreads();
    *(bfrag8*)((char*)As + wo0) = ra0;
    *(bfrag8*)((char*)As + wo1) = ra1;
    *(bfrag8*)((char*)Bs + wo0) = rb0;
    *(bfrag8*)((char*)Bs + wo1) = rb1;
    __syncthreads();
    if (i<15){
      ga += 32; gw += 32;
      ra0 = *(const bfrag8*)(ga);
      ra1 = *(const bfrag8*)(ga+8);
      rb0 = *(const bfrag8*)(gw);
      rb1 = *(const bfrag8*)(gw+8);
    }
    bfrag8 af[4], bf[4];
    #pragma unroll
    for (int q=0;q<4;q++){
      af[q] = *(const bfrag8*)((char*)As + raoff[q]);
      bf[q] = *(const bfrag8*)((char*)Bs + rboff[q]);
    }
    #pragma unroll
    for (int mi=0;mi<4;mi++)
      #pragma unroll
      for (int ni=0;ni<4;ni++)
        acc[mi][ni] = __builtin_amdgcn_mfma_f32_16x16x32_bf16(af[mi], bf[ni], acc[mi][ni], 0,0,0);
  }

  #pragma unroll
  for (int mi=0;mi<4;mi++){
    int row = m0 + wr*64 + mi*16 + kg2*4;
    #pragma unroll
    for (int ni=0;ni<4;ni++){
      int col = n0 + wc*64 + ni*16 + lr;
      float bl = b_log[col];
      #pragma unroll
      for (int q=0;q<4;q++){
        float v = acc[mi][ni][q] + bl;
        out[(size_t)(row+q)*32050 + col] = (v == 0.0f) ? -INF_F : v;
      }
    }
  }
}

// ---------------- scatter-max of energies into extended logits (+ OOV fill) ---------
// 512 threads: s = tid (<400); lanes 400-449 fill OOV; branch-free unrolled dedupe scan
__global__ __launch_bounds__(512) void k_scatter(const int* __restrict__ ext_src,
    float* __restrict__ out) {
  __shared__ int tok[400];
  __shared__ float ev[400];
  int rr = blockIdx.x;
  int b = rr & 31;
  int tid = threadIdx.x;
  if (tid >= 400 && tid < 450)
    out[(size_t)rr*32050 + 32000 + (tid-400)] = -INF_F;
  if (tid < 400){
    tok[tid] = ext_src[b*400+tid];
    ev[tid]  = out[OFF_E + (size_t)rr*400 + tid];
  }
  __syncthreads();
  if (tid < 400){
    int tk = tok[tid];
    float m = -3.4e38f;
    bool pre = false;   // an earlier s2 with same token?
    #pragma unroll 1
    for (int s2=0; s2<400; s2+=8){
      #pragma unroll
      for (int q=0;q<8;q++){
        int tk2 = tok[s2+q];
        float e2 = ev[s2+q];
        bool eq = (tk2==tk);
        m = fmaxf(m, eq ? e2 : -3.4e38f);
        pre = pre || (eq && (s2+q) < tid);
      }
    }
    if (!pre && m != -INF_F){
      size_t idx = (size_t)rr*32050 + tk;
      float wv = out[idx];
      float extv = (wv == -INF_F) ? 0.0f : wv;
      float nv = extv + m;
      out[idx] = (nv == 0.0f) ? -INF_F : nv;
    }
  }
}

extern "C" void kernel_launch(void* const* d_in, const int* in_sizes, int n_in,
                              void* d_out, int out_size, void* d_ws, size_t ws_size,
                              hipStream_t stream) {
  const float* trg   = (const float*)d_in[0];
  const int*   ext   = (const int*)  d_in[1];
  const float* inits = (const float*)d_in[2];
  const float* enc   = (const float*)d_in[3];
  const int*   emask = (const int*)  d_in[4];
  const float* W_enc = (const float*)d_in[5];
  const float* b_enc = (const float*)d_in[6];
  const float* W_red = (const float*)d_in[7];
  const float* b_red = (const float*)d_in[8];
  const float* W_ih  = (const float*)d_in[9];
  const float* W_hh  = (const float*)d_in[10];
  const float* b_ih  = (const float*)d_in[11];
  const float* b_hh  = (const float*)d_in[12];
  const float* W_cat = (const float*)d_in[13];
  const float* b_cat = (const float*)d_in[14];
  const float* W_log = (const float*)d_in[15];
  const float* b_log = (const float*)d_in[16];
  float* out = (float*)d_out;
  float* ws  = (float*)d_ws;

  float* mem   = ws + 0ull;          // 6,553,600
  float* Wg    = ws + 6553600ull;    // 2,097,152
  float* Wct   = ws + 8650752ull;    // 1,662,976
  float* Gemb  = ws + 10313728ull;   // 2,097,152
  float* bcomb = ws + 12410880ull;   // 2,048
  float* hbuf  = ws + 12412928ull;   // 16,384
  float* c0    = ws + 12429312ull;   // 16,384
  float* c1    = ws + 12445696ull;   // 16,384
  float* ctxb  = ws + 12462080ull;   // 16,384
  float* hall  = ws + 12478464ull;   // 524,288
  float* ctxa  = ws + 13002752ull;   // 524,288
  float* cov   = ws + 13527040ull;   // 12,800
  float* part  = ws + 13539840ull;   // 524,288
  __hip_bfloat16* lib = (__hip_bfloat16*)(ws + 14590464ull);   // 262,144 floats
  __hip_bfloat16* wlb = (__hip_bfloat16*)(ws + 14852608ull);   // 8,192,000 floats
  // hi/lo split scratch OVERLAPS wlb (dead until k_wlogconv, which runs after k_memories)
  short* ehi = (short*)(ws + 14852608ull);   // 6,553,600 shorts
  short* elo = ehi + 6553600;                // 6,553,600 shorts
  short* whi = ehi + 13107200;               // 262,144 shorts
  short* wlo = ehi + 13369344;               // 262,144 shorts

  k_init<<<64,256,0,stream>>>(inits, hbuf, c0, ctxb, cov);
  k_bcombo<<<8,256,0,stream>>>(W_ih, b_red, b_ih, b_hh, bcomb);
  k_wcombo<<<dim3(13,32),256,0,stream>>>(W_ih, W_red, Wct);
  k_gemb<<<dim3(32,16),256,0,stream>>>(trg, Wct, bcomb, Gemb);
  k_wgpack<<<8192,256,0,stream>>>(Wct, W_hh, Wg);
  k_convsplit<<<6656,256,0,stream>>>(enc, W_enc, ehi, elo, whi, wlo);
  k_memories<<<dim3(100,4),256,0,stream>>>(ehi, elo, whi, wlo, b_enc, mem);
  k_wlogconv<<<16000,256,0,stream>>>(W_log, wlb);

  for (int t=0;t<32;t++){
    const float* c_in = (t&1) ? c1 : c0;
    float* c_out      = (t&1) ? c0 : c1;
    k_gates<<<dim3(8,16),256,0,stream>>>(ctxb, hbuf, Wg, part);
    k_lstm_energy<<<256,256,0,stream>>>(part, Gemb, c_in, c_out, hbuf, hall,
                                        mem, emask, out, t);
    k_ctx<<<128,256,0,stream>>>(out, mem, ctxb, ctxa, cov, t);
  }

  k_logitin<<<dim3(8,4),256,0,stream>>>(hall, ctxa, W_cat, b_cat, lib);
  k_logits<<<dim3(8,250),256,0,stream>>>(lib, wlb, b_log, out);
  k_scatter<<<1024,512,0,stream>>>(ext, out);
}